// Round 9
// baseline (621.478 us; speedup 1.0000x reference)
//
#include <hip/hip_runtime.h>
#include <hip/hip_bf16.h>
#include <hip/hip_fp16.h>
#include <math.h>

#define NNODES 50000

typedef __attribute__((ext_vector_type(8))) short short8v;
typedef __attribute__((ext_vector_type(4))) float f32x4;
typedef unsigned short ushort_t;
typedef unsigned int uint_t;

// ---------------- bf16 / fp16 helpers ----------------
__device__ inline ushort_t f2bf_bits(float v) {
    union { __hip_bfloat16 b; ushort_t u; } c;
    c.b = __float2bfloat16(v);
    return c.u;
}
__device__ inline float bfbits2f(ushort_t u) {
    union { __hip_bfloat16 b; ushort_t u; } c;
    c.u = u;
    return __bfloat162float(c.b);
}
__device__ inline ushort_t f2h_bits(float v) {
    union { __half h; ushort_t u; } c;
    c.h = __float2half(v);
    return c.u;
}
__device__ inline void cvt2(uint_t u, float& a, float& b) {
    union { uint_t u; __half2 h; } c; c.u = u;
    a = __low2float(c.h); b = __high2float(c.h);
}
// monotone float<->uint mapping (for atomicMax on floats incl. negatives)
__device__ inline uint_t fmap(float f) {
    uint_t b = __float_as_uint(f);
    return (b & 0x80000000u) ? ~b : (b | 0x80000000u);
}
__device__ inline float funmap(uint_t u) {
    return __uint_as_float((u & 0x80000000u) ? (u & 0x7FFFFFFFu) : ~u);
}

// split fp32 -> (hi, lo) bf16 pair, vectorized x4
__global__ __launch_bounds__(256)
void split_kernel(const float4* __restrict__ in, ushort4* __restrict__ hi,
                  ushort4* __restrict__ lo, int n4) {
    int i = blockIdx.x * blockDim.x + threadIdx.x;
    if (i >= n4) return;
    float4 v = in[i];
    ushort4 h, l;
    h.x = f2bf_bits(v.x); l.x = f2bf_bits(v.x - bfbits2f(h.x));
    h.y = f2bf_bits(v.y); l.y = f2bf_bits(v.y - bfbits2f(h.y));
    h.z = f2bf_bits(v.z); l.z = f2bf_bits(v.z - bfbits2f(h.z));
    h.w = f2bf_bits(v.w); l.w = f2bf_bits(v.w - bfbits2f(h.w));
    hi[i] = h; lo[i] = l;
}

// all three weight transposes/splits in one launch
__global__ __launch_bounds__(256)
void wprep_all(const float* __restrict__ W1, const float* __restrict__ W2,
               const float* __restrict__ W3,
               ushort_t* __restrict__ w1h, ushort_t* __restrict__ w1l,
               ushort_t* __restrict__ w2h, ushort_t* __restrict__ w2l,
               ushort_t* __restrict__ w3h, ushort_t* __restrict__ w3l) {
    int idx = blockIdx.x * blockDim.x + threadIdx.x;
    const float* W; ushort_t* hT; ushort_t* lT; int K, N;
    if (idx < 128 * 256) { W = W1; hT = w1h; lT = w1l; K = 128; N = 256; }
    else if (idx < 128 * 256 + 256 * 256) {
        idx -= 128 * 256; W = W2; hT = w2h; lT = w2l; K = 256; N = 256;
    } else {
        idx -= 128 * 256 + 256 * 256;
        if (idx >= 256 * 384) return;
        W = W3; hT = w3h; lT = w3l; K = 256; N = 384;
    }
    int k = idx / N, n = idx - k * N;
    float v = W[idx];
    ushort_t hb = f2bf_bits(v);
    hT[(size_t)n * K + k] = hb;
    lT[(size_t)n * K + k] = f2bf_bits(v - bfbits2f(hb));
}

// ============ fused split-bf16 3-pass MFMA GEMM + pack + score ==============
// C = A[M][K] * B[K][N] (B stored transposed [N][K], hi/lo bf16).
// BM=128, BN=128 (exactly 2 heads), BK=32, 4 waves of 64x64, reg-staged LDS.
// Epilogue: acc -> LDS fp16 (XOR-swizzled) -> head-pair plane h16[p][n][c][2],
// fused s_src/s_dst dot-reduce, and per-head global max (monotone-uint atomicMax).
template<int H>
__global__ __launch_bounds__(256)
void gemm_fused(const ushort_t* __restrict__ Ahi, const ushort_t* __restrict__ Alo,
                const ushort_t* __restrict__ Bhi, const ushort_t* __restrict__ Blo,
                ushort_t* __restrict__ h16, float* __restrict__ ssrc,
                float* __restrict__ sdst, uint_t* __restrict__ gmaxu,
                const float* __restrict__ a_src, const float* __restrict__ a_dst,
                int M, int K) {
    __shared__ char smem[32768];            // staging (4x8KB) / epilogue h2 union
    __shared__ float sSs[128][2], sDs[128][2];
    __shared__ uint_t gblk[2];

    const int tid = threadIdx.x;
    const int lane = tid & 63;
    const int wid = tid >> 6;
    const int wm = wid >> 1, wn = wid & 1;
    const int bm = blockIdx.y * 128;
    const int bn = blockIdx.x * 128;
    const int r15 = lane & 15;
    const int g4 = lane >> 4;

    if (tid < 128) { sSs[tid][0] = 0.f; sSs[tid][1] = 0.f;
                     sDs[tid][0] = 0.f; sDs[tid][1] = 0.f; }
    if (tid < 2) gblk[tid] = 0;

    char* As_hi = smem;
    char* As_lo = smem + 8192;
    char* Bs_hi = smem + 16384;
    char* Bs_lo = smem + 24576;

    const int srow = tid >> 1;          // staging row 0..127
    const int sch  = (tid & 1) * 2;     // staging k-chunk base (0 or 2)
    const size_t arow = (size_t)(bm + srow) * K;
    const size_t brow = (size_t)(bn + srow) * K;

    f32x4 acc[4][4] = {};

    for (int k0 = 0; k0 < K; k0 += 32) {
        // issue global loads (rows >= M read adjacent ws buffers: safe, never stored)
        short8v a0 = *(const short8v*)&Ahi[arow + k0 + sch * 8];
        short8v a1 = *(const short8v*)&Ahi[arow + k0 + sch * 8 + 8];
        short8v l0 = *(const short8v*)&Alo[arow + k0 + sch * 8];
        short8v l1 = *(const short8v*)&Alo[arow + k0 + sch * 8 + 8];
        short8v b0 = *(const short8v*)&Bhi[brow + k0 + sch * 8];
        short8v b1 = *(const short8v*)&Bhi[brow + k0 + sch * 8 + 8];
        short8v m0 = *(const short8v*)&Blo[brow + k0 + sch * 8];
        short8v m1 = *(const short8v*)&Blo[brow + k0 + sch * 8 + 8];
        __syncthreads();                 // previous iteration's reads done
        *(short8v*)(As_hi + sch * 2048 + srow * 16)       = a0;
        *(short8v*)(As_hi + (sch + 1) * 2048 + srow * 16) = a1;
        *(short8v*)(As_lo + sch * 2048 + srow * 16)       = l0;
        *(short8v*)(As_lo + (sch + 1) * 2048 + srow * 16) = l1;
        *(short8v*)(Bs_hi + sch * 2048 + srow * 16)       = b0;
        *(short8v*)(Bs_hi + (sch + 1) * 2048 + srow * 16) = b1;
        *(short8v*)(Bs_lo + sch * 2048 + srow * 16)       = m0;
        *(short8v*)(Bs_lo + (sch + 1) * 2048 + srow * 16) = m1;
        __syncthreads();

        short8v ah[4], al[4], bh[4], bl[4];
        #pragma unroll
        for (int mi = 0; mi < 4; ++mi) {
            int row = wm * 64 + mi * 16 + r15;
            ah[mi] = *(const short8v*)(As_hi + g4 * 2048 + row * 16);
            al[mi] = *(const short8v*)(As_lo + g4 * 2048 + row * 16);
        }
        #pragma unroll
        for (int nj = 0; nj < 4; ++nj) {
            int row = wn * 64 + nj * 16 + r15;
            bh[nj] = *(const short8v*)(Bs_hi + g4 * 2048 + row * 16);
            bl[nj] = *(const short8v*)(Bs_lo + g4 * 2048 + row * 16);
        }
        #pragma unroll
        for (int mi = 0; mi < 4; ++mi)
            #pragma unroll
            for (int nj = 0; nj < 4; ++nj) {
                acc[mi][nj] = __builtin_amdgcn_mfma_f32_16x16x32_bf16(ah[mi], bh[nj], acc[mi][nj], 0, 0, 0);
                acc[mi][nj] = __builtin_amdgcn_mfma_f32_16x16x32_bf16(ah[mi], bl[nj], acc[mi][nj], 0, 0, 0);
                acc[mi][nj] = __builtin_amdgcn_mfma_f32_16x16x32_bf16(al[mi], bh[nj], acc[mi][nj], 0, 0, 0);
            }
    }
    __syncthreads();                    // all waves done reading staging LDS

    // ---- epilogue: h2 transpose + fused scores ----
    ushort_t* h2 = (ushort_t*)smem;     // [128 rows][128 cols] fp16, col XOR-swizzle
    const int headg = (bn >> 6) + wn;   // global head of this wave's 64-col slice
    float asv[4], adv[4];
    #pragma unroll
    for (int nj = 0; nj < 4; ++nj) {
        asv[nj] = a_src[headg * 64 + nj * 16 + r15];
        adv[nj] = a_dst[headg * 64 + nj * 16 + r15];
    }
    #pragma unroll
    for (int mi = 0; mi < 4; ++mi) {
        #pragma unroll
        for (int reg = 0; reg < 4; ++reg) {
            int row_l = wm * 64 + mi * 16 + g4 * 4 + reg;
            int csw = ((row_l >> 2) & 3) << 2;
            float pS = 0.f, pD = 0.f;
            #pragma unroll
            for (int nj = 0; nj < 4; ++nj) {
                float v = acc[mi][nj][reg];
                int col_l = wn * 64 + nj * 16 + r15;
                h2[row_l * 128 + (col_l ^ csw)] = f2h_bits(v);
                pS += v * asv[nj];
                pD += v * adv[nj];
            }
            #pragma unroll
            for (int off = 1; off < 16; off <<= 1) {   // reduce over the 16 r15 lanes
                pS += __shfl_xor(pS, off);
                pD += __shfl_xor(pD, off);
            }
            if (r15 == 0 && bm + row_l < M) {
                atomicAdd(&sSs[row_l][wn], pS);
                atomicAdd(&sDs[row_l][wn], pD);
            }
        }
    }
    __syncthreads();

    // h16 plane write: plane p = bn/128; per node 64 uint (=256B) contiguous
    uint_t* plane = (uint_t*)h16 + (size_t)(bn >> 7) * ((size_t)NNODES * 64);
    for (int u = tid; u < 128 * 64; u += 256) {
        int n_l = u >> 6, c = u & 63;
        if (bm + n_l < M) {
            int csw = ((n_l >> 2) & 3) << 2;
            uint_t lo = h2[n_l * 128 + (c ^ csw)];
            uint_t hi = h2[n_l * 128 + 64 + (c ^ csw)];
            plane[(size_t)(bm + n_l) * 64 + c] = lo | (hi << 16);
        }
    }
    // scores out + per-head block max
    {
        int row = tid >> 1, hl = tid & 1;
        if (bm + row < M) {
            int hg = (bn >> 6) + hl;
            float vS = sSs[row][hl];
            ssrc[(size_t)(bm + row) * H + hg] = vS;
            sdst[(size_t)(bm + row) * H + hg] = sDs[row][hl];
            atomicMax(&gblk[hl], fmap(vS));
        }
    }
    __syncthreads();
    if (tid < 2) atomicMax(&gmaxu[(bn >> 6) + tid], gblk[tid]);
}

// ============================ CSR build =====================================
__global__ void deg_kernel(const int* __restrict__ ei, int E, int Nn,
                           int* __restrict__ deg) {
    int e = blockIdx.x * blockDim.x + threadIdx.x;
    int tot = E + Nn;
    if (e >= tot) return;
    int d = (e < E) ? ei[E + e] : (e - E);
    atomicAdd(&deg[d], 1);
}

// two-level scan: (1) per-block local inclusive scan, (2) 1-wave scan of block
// sums, (3) add carries + derive cursor
__global__ __launch_bounds__(1024)
void scan1_kernel(const int* __restrict__ deg, int* __restrict__ offs,
                  int* __restrict__ bsum, int n) {
    __shared__ int sh[1024];
    int t = threadIdx.x;
    int i = blockIdx.x * 1024 + t;
    int v = (i < n) ? deg[i] : 0;
    sh[t] = v;
    __syncthreads();
    for (int off = 1; off < 1024; off <<= 1) {
        int add = (t >= off) ? sh[t - off] : 0;
        __syncthreads();
        sh[t] += add;
        __syncthreads();
    }
    if (i < n) offs[i + 1] = sh[t];
    if (t == 1023) bsum[blockIdx.x] = sh[1023];
}

__global__ __launch_bounds__(64)
void scan2_kernel(const int* __restrict__ bsum, int* __restrict__ bexcl, int nb) {
    int t = threadIdx.x;
    int v = (t < nb) ? bsum[t] : 0;
    int orig = v;
    #pragma unroll
    for (int off = 1; off < 64; off <<= 1) {
        int u = __shfl_up(v, off);
        if (t >= off) v += u;
    }
    if (t < nb) bexcl[t] = v - orig;
}

__global__ void scan3_kernel(const int* __restrict__ deg, int* __restrict__ offs,
                             const int* __restrict__ bexcl, int* __restrict__ cursor,
                             int n) {
    int i = blockIdx.x * blockDim.x + threadIdx.x;
    if (i == 0) offs[0] = 0;
    if (i < n) {
        int inc = offs[i + 1] + bexcl[i >> 10];
        offs[i + 1] = inc;
        cursor[i] = inc - deg[i];
    }
}

__global__ void scatter_kernel(const int* __restrict__ ei, int E, int Nn,
                               int* __restrict__ cursor, int* __restrict__ csr_src) {
    int e = blockIdx.x * blockDim.x + threadIdx.x;
    int tot = E + Nn;
    if (e >= tot) return;
    int s, d;
    if (e < E) { s = ei[e]; d = ei[E + e]; }
    else       { s = d = e - E; }
    int pos = atomicAdd(&cursor[d], 1);
    csr_src[pos] = s;
}

// ---------------- vector load of ssrc row [H floats] ----------------
template<int H>
__device__ inline void loadS(const float* __restrict__ p, float* v) {
    if constexpr (H == 4) {
        float4 t = *(const float4*)p;
        v[0] = t.x; v[1] = t.y; v[2] = t.z; v[3] = t.w;
    } else {
        const float2* q = (const float2*)p;
        float2 a = q[0], b = q[1], c = q[2];
        v[0] = a.x; v[1] = a.y; v[2] = b.x; v[3] = b.y; v[4] = c.x; v[5] = c.y;
    }
}

// ====== fused aggregation: inline softmax weights + fp16 plane gathers ======
// wave per node, lane = channel. Per edge: csr (wave-uniform), ssrc[s]
// broadcast load (same addr all lanes -> 1 line, L2-resident), H exps
// (redundant across lanes, cheap), H/2 plane gathers. All lanes accumulate
// the identical denominator -> no reduction. Global-max shift (exact in alpha).
template<int H, bool MEAN>
__global__ __launch_bounds__(256)
void agg_kernel(const ushort_t* __restrict__ h16, const float* __restrict__ ssrc,
                const float* __restrict__ sdst, const uint_t* __restrict__ gmaxu,
                const int* __restrict__ offs, const int* __restrict__ csr,
                const float* __restrict__ bias, float* __restrict__ outf,
                ushort_t* __restrict__ ohi, ushort_t* __restrict__ olo, int Nn) {
    constexpr int P = H / 2;
    int wid = (blockIdx.x * blockDim.x + threadIdx.x) >> 6;
    int lane = threadIdx.x & 63;
    if (wid >= Nn) return;
    int beg = offs[wid], end = offs[wid + 1];
    const uint_t* up = (const uint_t*)h16;
    const size_t psz = (size_t)Nn * 64;

    float sd[H], mx[H];
    #pragma unroll
    for (int h = 0; h < H; ++h) {
        sd[h] = sdst[wid * H + h];
        float t = funmap(gmaxu[h]) + sd[h];
        mx[h] = t > 0.f ? t : 0.2f * t;     // leaky monotone: >= all edge scores
    }

    constexpr int U = (H == 4) ? 8 : 4;
    float acc0[H] = {}, acc1[H] = {};
    float den0[H] = {}, den1[H] = {};
    int i = beg;
    for (; i + U <= end; i += U) {
        int s[U];
        #pragma unroll
        for (int j = 0; j < U; ++j) s[j] = csr[i + j];
        uint_t g[U][P];
        #pragma unroll
        for (int j = 0; j < U; ++j)
            #pragma unroll
            for (int p = 0; p < P; ++p)
                g[j][p] = up[(size_t)p * psz + (size_t)s[j] * 64 + lane];
        float sv[U][H];
        #pragma unroll
        for (int j = 0; j < U; ++j) loadS<H>(ssrc + (size_t)s[j] * H, sv[j]);
        #pragma unroll
        for (int j = 0; j < U; ++j) {
            float w[H], v[H];
            #pragma unroll
            for (int h = 0; h < H; ++h) {
                float sc = sv[j][h] + sd[h];
                sc = sc > 0.f ? sc : 0.2f * sc;
                w[h] = __expf(sc - mx[h]);
            }
            #pragma unroll
            for (int p = 0; p < P; ++p) cvt2(g[j][p], v[2 * p], v[2 * p + 1]);
            float* a = (j & 1) ? acc1 : acc0;
            float* d = (j & 1) ? den1 : den0;
            #pragma unroll
            for (int h = 0; h < H; ++h) { a[h] += w[h] * v[h]; d[h] += w[h]; }
        }
    }
    for (; i < end; ++i) {
        int s = csr[i];
        float sv[H], v[H];
        loadS<H>(ssrc + (size_t)s * H, sv);
        #pragma unroll
        for (int p = 0; p < P; ++p) {
            uint_t g = up[(size_t)p * psz + (size_t)s * 64 + lane];
            cvt2(g, v[2 * p], v[2 * p + 1]);
        }
        #pragma unroll
        for (int h = 0; h < H; ++h) {
            float sc = sv[h] + sd[h];
            sc = sc > 0.f ? sc : 0.2f * sc;
            float w = __expf(sc - mx[h]);
            acc0[h] += w * v[h];
            den0[h] += w;
        }
    }

    if (!MEAN) {
        #pragma unroll
        for (int h = 0; h < H; ++h) {
            float val = (acc0[h] + acc1[h]) / (den0[h] + den1[h] + 1e-16f)
                        + bias[h * 64 + lane];
            val = val > 0.f ? val : expm1f(val);   // ELU
            size_t idx = (size_t)wid * (H * 64) + h * 64 + lane;
            ushort_t hb = f2bf_bits(val);
            ohi[idx] = hb;
            olo[idx] = f2bf_bits(val - bfbits2f(hb));
        }
    } else {
        float m = 0.f;
        #pragma unroll
        for (int h = 0; h < H; ++h)
            m += (acc0[h] + acc1[h]) / (den0[h] + den1[h] + 1e-16f);
        outf[(size_t)wid * 64 + lane] = m * (1.f / (float)H) + bias[lane];
    }
}

// ============================ launch ========================================
extern "C" void kernel_launch(void* const* d_in, const int* in_sizes, int n_in,
                              void* d_out, int out_size, void* d_ws, size_t ws_size,
                              hipStream_t stream) {
    const float* x     = (const float*)d_in[0];
    const int*   ei    = (const int*)d_in[1];
    const float* W1    = (const float*)d_in[2];
    const float* a1s   = (const float*)d_in[3];
    const float* a1d   = (const float*)d_in[4];
    const float* b1    = (const float*)d_in[5];
    const float* W2    = (const float*)d_in[6];
    const float* a2s   = (const float*)d_in[7];
    const float* a2d   = (const float*)d_in[8];
    const float* b2    = (const float*)d_in[9];
    const float* W3    = (const float*)d_in[10];
    const float* a3s   = (const float*)d_in[11];
    const float* a3d   = (const float*)d_in[12];
    const float* b3    = (const float*)d_in[13];
    float* out = (float*)d_out;

    const int Nn = NNODES;
    const int E  = in_sizes[1] / 2;
    const int Etot = E + Nn;

    char* p = (char*)d_ws;
    auto carve = [&](size_t bytes) {
        char* r = p;
        p += (bytes + 255) & ~(size_t)255;
        return (void*)r;
    };
    ushort_t* h16   = (ushort_t*)carve((size_t)Nn * 384 * 2);   // up to 3 planes
    ushort_t* R1    = (ushort_t*)carve((size_t)Nn * 256 * 4);
    ushort_t* x_hi  = R1;
    ushort_t* x_lo  = R1 + (size_t)Nn * 128;
    ushort_t* x1_hi = R1;
    ushort_t* x1_lo = R1 + (size_t)Nn * 256;
    ushort_t* w1hi  = (ushort_t*)carve((size_t)128 * 256 * 2);
    ushort_t* w1lo  = (ushort_t*)carve((size_t)128 * 256 * 2);
    ushort_t* w2hi  = (ushort_t*)carve((size_t)256 * 256 * 2);
    ushort_t* w2lo  = (ushort_t*)carve((size_t)256 * 256 * 2);
    ushort_t* w3hi  = (ushort_t*)carve((size_t)256 * 384 * 2);
    ushort_t* w3lo  = (ushort_t*)carve((size_t)256 * 384 * 2);
    float* ssrc   = (float*)carve((size_t)Nn * 6 * 4);
    float* sdst   = (float*)carve((size_t)Nn * 6 * 4);
    int*   deg    = (int*)carve((size_t)Nn * 4);
    int*   offs   = (int*)carve((size_t)(Nn + 1) * 4);
    int*   cursor = (int*)carve((size_t)Nn * 4);
    int*   csr    = (int*)carve((size_t)Etot * 4);
    uint_t* gmaxu = (uint_t*)carve(18 * 4);
    int*   bsum   = (int*)carve(64 * 4);
    int*   bexcl  = (int*)carve(64 * 4);

    // -------- CSR build --------
    hipMemsetAsync(deg, 0, (size_t)Nn * 4, stream);
    hipMemsetAsync(gmaxu, 0, 18 * 4, stream);   // 0 == fmap(-inf) lower bound
    {
        int nb = (Etot + 255) / 256;
        int nsb = (Nn + 1023) / 1024;
        deg_kernel<<<nb, 256, 0, stream>>>(ei, E, Nn, deg);
        scan1_kernel<<<nsb, 1024, 0, stream>>>(deg, offs, bsum, Nn);
        scan2_kernel<<<1, 64, 0, stream>>>(bsum, bexcl, nsb);
        scan3_kernel<<<(Nn + 255) / 256, 256, 0, stream>>>(deg, offs, bexcl, cursor, Nn);
        scatter_kernel<<<nb, 256, 0, stream>>>(ei, E, Nn, cursor, csr);
    }

    // -------- weight + input prep --------
    {
        int n4 = Nn * 128 / 4;
        split_kernel<<<(n4 + 255) / 256, 256, 0, stream>>>(
            (const float4*)x, (ushort4*)x_hi, (ushort4*)x_lo, n4);
        int wtot = 128 * 256 + 256 * 256 + 256 * 384;
        wprep_all<<<(wtot + 255) / 256, 256, 0, stream>>>(W1, W2, W3, w1hi, w1lo,
                                                          w2hi, w2lo, w3hi, w3lo);
    }

    const int node_blocks = (Nn + 3) / 4;
    const int gemm_rows = (Nn + 127) / 128;

    // -------- layer 1: [50000,128] @ [128,256], H=4, concat+ELU --------
    {
        dim3 g(2, gemm_rows);
        gemm_fused<4><<<g, 256, 0, stream>>>(x_hi, x_lo, w1hi, w1lo, h16,
                                             ssrc, sdst, gmaxu + 0, a1s, a1d, Nn, 128);
        agg_kernel<4, false><<<node_blocks, 256, 0, stream>>>(h16, ssrc, sdst, gmaxu + 0,
                                                              offs, csr, b1,
                                                              nullptr, x1_hi, x1_lo, Nn);
    }
    // -------- layer 2: [50000,256] @ [256,256], H=4, concat+ELU --------
    {
        dim3 g(2, gemm_rows);
        gemm_fused<4><<<g, 256, 0, stream>>>(x1_hi, x1_lo, w2hi, w2lo, h16,
                                             ssrc, sdst, gmaxu + 6, a2s, a2d, Nn, 256);
        agg_kernel<4, false><<<node_blocks, 256, 0, stream>>>(h16, ssrc, sdst, gmaxu + 6,
                                                              offs, csr, b2,
                                                              nullptr, x1_hi, x1_lo, Nn);
    }
    // -------- layer 3: [50000,256] @ [256,384], H=6, mean --------
    {
        dim3 g(3, gemm_rows);
        gemm_fused<6><<<g, 256, 0, stream>>>(x1_hi, x1_lo, w3hi, w3lo, h16,
                                             ssrc, sdst, gmaxu + 12, a3s, a3d, Nn, 256);
        agg_kernel<6, true><<<node_blocks, 256, 0, stream>>>(h16, ssrc, sdst, gmaxu + 12,
                                                             offs, csr, b3,
                                                             out, nullptr, nullptr, Nn);
    }
}

// Round 10
// 595.524 us; speedup vs baseline: 1.0436x; 1.0436x over previous
//
#include <hip/hip_runtime.h>
#include <hip/hip_bf16.h>
#include <hip/hip_fp16.h>
#include <math.h>

#define NNODES 50000

typedef __attribute__((ext_vector_type(8))) short short8v;
typedef __attribute__((ext_vector_type(4))) float f32x4;
typedef unsigned short ushort_t;
typedef unsigned int uint_t;

// ---------------- bf16 / fp16 helpers ----------------
__device__ inline ushort_t f2bf_bits(float v) {
    union { __hip_bfloat16 b; ushort_t u; } c;
    c.b = __float2bfloat16(v);
    return c.u;
}
__device__ inline float bfbits2f(ushort_t u) {
    union { __hip_bfloat16 b; ushort_t u; } c;
    c.u = u;
    return __bfloat162float(c.b);
}
__device__ inline ushort_t f2h_bits(float v) {
    union { __half h; ushort_t u; } c;
    c.h = __float2half(v);
    return c.u;
}
__device__ inline void cvt2(uint_t u, float& a, float& b) {
    union { uint_t u; __half2 h; } c; c.u = u;
    a = __low2float(c.h); b = __high2float(c.h);
}
// monotone float<->uint mapping (for atomicMax on floats incl. negatives)
__device__ inline uint_t fmap(float f) {
    uint_t b = __float_as_uint(f);
    return (b & 0x80000000u) ? ~b : (b | 0x80000000u);
}
__device__ inline float funmap(uint_t u) {
    return __uint_as_float((u & 0x80000000u) ? (u & 0x7FFFFFFFu) : ~u);
}

// split fp32 -> (hi, lo) bf16 pair, vectorized x4
__global__ __launch_bounds__(256)
void split_kernel(const float4* __restrict__ in, ushort4* __restrict__ hi,
                  ushort4* __restrict__ lo, int n4) {
    int i = blockIdx.x * blockDim.x + threadIdx.x;
    if (i >= n4) return;
    float4 v = in[i];
    ushort4 h, l;
    h.x = f2bf_bits(v.x); l.x = f2bf_bits(v.x - bfbits2f(h.x));
    h.y = f2bf_bits(v.y); l.y = f2bf_bits(v.y - bfbits2f(h.y));
    h.z = f2bf_bits(v.z); l.z = f2bf_bits(v.z - bfbits2f(h.z));
    h.w = f2bf_bits(v.w); l.w = f2bf_bits(v.w - bfbits2f(h.w));
    hi[i] = h; lo[i] = l;
}

// all three weight transposes/splits in one launch
__global__ __launch_bounds__(256)
void wprep_all(const float* __restrict__ W1, const float* __restrict__ W2,
               const float* __restrict__ W3,
               ushort_t* __restrict__ w1h, ushort_t* __restrict__ w1l,
               ushort_t* __restrict__ w2h, ushort_t* __restrict__ w2l,
               ushort_t* __restrict__ w3h, ushort_t* __restrict__ w3l) {
    int idx = blockIdx.x * blockDim.x + threadIdx.x;
    const float* W; ushort_t* hT; ushort_t* lT; int K, N;
    if (idx < 128 * 256) { W = W1; hT = w1h; lT = w1l; K = 128; N = 256; }
    else if (idx < 128 * 256 + 256 * 256) {
        idx -= 128 * 256; W = W2; hT = w2h; lT = w2l; K = 256; N = 256;
    } else {
        idx -= 128 * 256 + 256 * 256;
        if (idx >= 256 * 384) return;
        W = W3; hT = w3h; lT = w3l; K = 256; N = 384;
    }
    int k = idx / N, n = idx - k * N;
    float v = W[idx];
    ushort_t hb = f2bf_bits(v);
    hT[(size_t)n * K + k] = hb;
    lT[(size_t)n * K + k] = f2bf_bits(v - bfbits2f(hb));
}

// ============ fused split-bf16 3-pass MFMA GEMM + pack + score ==============
// C = A[M][K] * B[K][N] (B stored transposed [N][K], hi/lo bf16).
// BM=128, BN=128 (exactly 2 heads), BK=32, 4 waves of 64x64, reg-staged LDS.
// Grid is 1D with a bijective chunked XCD swizzle (col-inner order): all
// column-blocks of a row-block land on the SAME XCD so the A-panel is fetched
// through that XCD's L2 once instead of NC times.
// Epilogue: acc -> LDS fp16 (XOR-swizzled) -> head-pair plane h16[p][n][c][2],
// fused s_src/s_dst dot-reduce, and per-head global max (monotone-uint atomicMax).
template<int H>
__global__ __launch_bounds__(256)
void gemm_fused(const ushort_t* __restrict__ Ahi, const ushort_t* __restrict__ Alo,
                const ushort_t* __restrict__ Bhi, const ushort_t* __restrict__ Blo,
                ushort_t* __restrict__ h16, float* __restrict__ ssrc,
                float* __restrict__ sdst, uint_t* __restrict__ gmaxu,
                const float* __restrict__ a_src, const float* __restrict__ a_dst,
                int NC, int M, int K) {
    __shared__ char smem[32768];            // staging (4x8KB) / epilogue h2 union
    __shared__ float sSs[128][2], sDs[128][2];
    __shared__ uint_t gblk[2];

    // ---- bijective chunked XCD swizzle (m204): orig%8 = XCD ----
    const int nwg = gridDim.x;
    int orig = blockIdx.x;
    int q = nwg >> 3, r = nwg & 7;
    int xcd = orig & 7, off = orig >> 3;
    int t = (xcd < r ? xcd * (q + 1) : r * (q + 1) + (xcd - r) * q) + off;
    const int bn = (t % NC) * 128;          // col-inner: row's cols contiguous
    const int bm = (t / NC) * 128;

    const int tid = threadIdx.x;
    const int lane = tid & 63;
    const int wid = tid >> 6;
    const int wm = wid >> 1, wn = wid & 1;
    const int r15 = lane & 15;
    const int g4 = lane >> 4;

    if (tid < 128) { sSs[tid][0] = 0.f; sSs[tid][1] = 0.f;
                     sDs[tid][0] = 0.f; sDs[tid][1] = 0.f; }
    if (tid < 2) gblk[tid] = 0;

    char* As_hi = smem;
    char* As_lo = smem + 8192;
    char* Bs_hi = smem + 16384;
    char* Bs_lo = smem + 24576;

    const int srow = tid >> 1;          // staging row 0..127
    const int sch  = (tid & 1) * 2;     // staging k-chunk base (0 or 2)
    const size_t arow = (size_t)(bm + srow) * K;
    const size_t brow = (size_t)(bn + srow) * K;

    f32x4 acc[4][4] = {};

    for (int k0 = 0; k0 < K; k0 += 32) {
        // issue global loads (rows >= M read adjacent ws buffers: safe, never stored)
        short8v a0 = *(const short8v*)&Ahi[arow + k0 + sch * 8];
        short8v a1 = *(const short8v*)&Ahi[arow + k0 + sch * 8 + 8];
        short8v l0 = *(const short8v*)&Alo[arow + k0 + sch * 8];
        short8v l1 = *(const short8v*)&Alo[arow + k0 + sch * 8 + 8];
        short8v b0 = *(const short8v*)&Bhi[brow + k0 + sch * 8];
        short8v b1 = *(const short8v*)&Bhi[brow + k0 + sch * 8 + 8];
        short8v m0 = *(const short8v*)&Blo[brow + k0 + sch * 8];
        short8v m1 = *(const short8v*)&Blo[brow + k0 + sch * 8 + 8];
        __syncthreads();                 // previous iteration's reads done
        *(short8v*)(As_hi + sch * 2048 + srow * 16)       = a0;
        *(short8v*)(As_hi + (sch + 1) * 2048 + srow * 16) = a1;
        *(short8v*)(As_lo + sch * 2048 + srow * 16)       = l0;
        *(short8v*)(As_lo + (sch + 1) * 2048 + srow * 16) = l1;
        *(short8v*)(Bs_hi + sch * 2048 + srow * 16)       = b0;
        *(short8v*)(Bs_hi + (sch + 1) * 2048 + srow * 16) = b1;
        *(short8v*)(Bs_lo + sch * 2048 + srow * 16)       = m0;
        *(short8v*)(Bs_lo + (sch + 1) * 2048 + srow * 16) = m1;
        __syncthreads();

        short8v ah[4], al[4], bh[4], bl[4];
        #pragma unroll
        for (int mi = 0; mi < 4; ++mi) {
            int row = wm * 64 + mi * 16 + r15;
            ah[mi] = *(const short8v*)(As_hi + g4 * 2048 + row * 16);
            al[mi] = *(const short8v*)(As_lo + g4 * 2048 + row * 16);
        }
        #pragma unroll
        for (int nj = 0; nj < 4; ++nj) {
            int row = wn * 64 + nj * 16 + r15;
            bh[nj] = *(const short8v*)(Bs_hi + g4 * 2048 + row * 16);
            bl[nj] = *(const short8v*)(Bs_lo + g4 * 2048 + row * 16);
        }
        #pragma unroll
        for (int mi = 0; mi < 4; ++mi)
            #pragma unroll
            for (int nj = 0; nj < 4; ++nj) {
                acc[mi][nj] = __builtin_amdgcn_mfma_f32_16x16x32_bf16(ah[mi], bh[nj], acc[mi][nj], 0, 0, 0);
                acc[mi][nj] = __builtin_amdgcn_mfma_f32_16x16x32_bf16(ah[mi], bl[nj], acc[mi][nj], 0, 0, 0);
                acc[mi][nj] = __builtin_amdgcn_mfma_f32_16x16x32_bf16(al[mi], bh[nj], acc[mi][nj], 0, 0, 0);
            }
    }
    __syncthreads();                    // all waves done reading staging LDS

    // ---- epilogue: h2 transpose + fused scores ----
    ushort_t* h2 = (ushort_t*)smem;     // [128 rows][128 cols] fp16, col XOR-swizzle
    const int headg = (bn >> 6) + wn;   // global head of this wave's 64-col slice
    float asv[4], adv[4];
    #pragma unroll
    for (int nj = 0; nj < 4; ++nj) {
        asv[nj] = a_src[headg * 64 + nj * 16 + r15];
        adv[nj] = a_dst[headg * 64 + nj * 16 + r15];
    }
    #pragma unroll
    for (int mi = 0; mi < 4; ++mi) {
        #pragma unroll
        for (int reg = 0; reg < 4; ++reg) {
            int row_l = wm * 64 + mi * 16 + g4 * 4 + reg;
            int csw = ((row_l >> 2) & 3) << 2;
            float pS = 0.f, pD = 0.f;
            #pragma unroll
            for (int nj = 0; nj < 4; ++nj) {
                float v = acc[mi][nj][reg];
                int col_l = wn * 64 + nj * 16 + r15;
                h2[row_l * 128 + (col_l ^ csw)] = f2h_bits(v);
                pS += v * asv[nj];
                pD += v * adv[nj];
            }
            #pragma unroll
            for (int off2 = 1; off2 < 16; off2 <<= 1) {  // reduce over 16 r15 lanes
                pS += __shfl_xor(pS, off2);
                pD += __shfl_xor(pD, off2);
            }
            if (r15 == 0 && bm + row_l < M) {
                atomicAdd(&sSs[row_l][wn], pS);
                atomicAdd(&sDs[row_l][wn], pD);
            }
        }
    }
    __syncthreads();

    // h16 plane write: plane p = bn/128; per node 64 uint (=256B) contiguous
    uint_t* plane = (uint_t*)h16 + (size_t)(bn >> 7) * ((size_t)NNODES * 64);
    for (int u = tid; u < 128 * 64; u += 256) {
        int n_l = u >> 6, c = u & 63;
        if (bm + n_l < M) {
            int csw = ((n_l >> 2) & 3) << 2;
            uint_t lo = h2[n_l * 128 + (c ^ csw)];
            uint_t hi = h2[n_l * 128 + 64 + (c ^ csw)];
            plane[(size_t)(bm + n_l) * 64 + c] = lo | (hi << 16);
        }
    }
    // scores out + per-head block max
    {
        int row = tid >> 1, hl = tid & 1;
        if (bm + row < M) {
            int hg = (bn >> 6) + hl;
            float vS = sSs[row][hl];
            ssrc[(size_t)(bm + row) * H + hg] = vS;
            sdst[(size_t)(bm + row) * H + hg] = sDs[row][hl];
            atomicMax(&gblk[hl], fmap(vS));
        }
    }
    __syncthreads();
    if (tid < 2) atomicMax(&gmaxu[(bn >> 6) + tid], gblk[tid]);
}

// ============================ CSR build =====================================
__global__ void deg_kernel(const int* __restrict__ ei, int E, int Nn,
                           int* __restrict__ deg) {
    int e = blockIdx.x * blockDim.x + threadIdx.x;
    int tot = E + Nn;
    if (e >= tot) return;
    int d = (e < E) ? ei[E + e] : (e - E);
    atomicAdd(&deg[d], 1);
}

// two-level scan: (1) per-block local inclusive scan, (2) 1-wave scan of block
// sums, (3) add carries + derive cursor
__global__ __launch_bounds__(1024)
void scan1_kernel(const int* __restrict__ deg, int* __restrict__ offs,
                  int* __restrict__ bsum, int n) {
    __shared__ int sh[1024];
    int t = threadIdx.x;
    int i = blockIdx.x * 1024 + t;
    int v = (i < n) ? deg[i] : 0;
    sh[t] = v;
    __syncthreads();
    for (int off = 1; off < 1024; off <<= 1) {
        int add = (t >= off) ? sh[t - off] : 0;
        __syncthreads();
        sh[t] += add;
        __syncthreads();
    }
    if (i < n) offs[i + 1] = sh[t];
    if (t == 1023) bsum[blockIdx.x] = sh[1023];
}

__global__ __launch_bounds__(64)
void scan2_kernel(const int* __restrict__ bsum, int* __restrict__ bexcl, int nb) {
    int t = threadIdx.x;
    int v = (t < nb) ? bsum[t] : 0;
    int orig = v;
    #pragma unroll
    for (int off = 1; off < 64; off <<= 1) {
        int u = __shfl_up(v, off);
        if (t >= off) v += u;
    }
    if (t < nb) bexcl[t] = v - orig;
}

__global__ void scan3_kernel(const int* __restrict__ deg, int* __restrict__ offs,
                             const int* __restrict__ bexcl, int* __restrict__ cursor,
                             int n) {
    int i = blockIdx.x * blockDim.x + threadIdx.x;
    if (i == 0) offs[0] = 0;
    if (i < n) {
        int inc = offs[i + 1] + bexcl[i >> 10];
        offs[i + 1] = inc;
        cursor[i] = inc - deg[i];
    }
}

__global__ void scatter_kernel(const int* __restrict__ ei, int E, int Nn,
                               int* __restrict__ cursor, int* __restrict__ csr_src) {
    int e = blockIdx.x * blockDim.x + threadIdx.x;
    int tot = E + Nn;
    if (e >= tot) return;
    int s, d;
    if (e < E) { s = ei[e]; d = ei[E + e]; }
    else       { s = d = e - E; }
    int pos = atomicAdd(&cursor[d], 1);
    csr_src[pos] = s;
}

// ---------------- vector load of ssrc row [H floats] ----------------
template<int H>
__device__ inline void loadS(const float* __restrict__ p, float* v) {
    if constexpr (H == 4) {
        float4 t = *(const float4*)p;
        v[0] = t.x; v[1] = t.y; v[2] = t.z; v[3] = t.w;
    } else {
        const float2* q = (const float2*)p;
        float2 a = q[0], b = q[1], c = q[2];
        v[0] = a.x; v[1] = a.y; v[2] = b.x; v[3] = b.y; v[4] = c.x; v[5] = c.y;
    }
}

// ==== single-pass: edge weights + recip denominator (global-max shift) ======
// m_d = leaky(gmax_h + sdst_d) >= max_e leaky(ssrc_e + sdst_d), exponent <= 0;
// per-destination shift cancels in alpha = w/den, so result is exact up to fp.
// lanes stride over edges -> each lane computes DIFFERENT edges' exps.
template<int H>
__global__ __launch_bounds__(256)
void smw_kernel(const float* __restrict__ ssrc, const float* __restrict__ sdst,
                const uint_t* __restrict__ gmaxu, const int* __restrict__ offs,
                const int* __restrict__ csr, float* __restrict__ wbuf,
                float* __restrict__ rden, int Nn) {
    int wid = (blockIdx.x * blockDim.x + threadIdx.x) >> 6;
    int lane = threadIdx.x & 63;
    if (wid >= Nn) return;
    int beg = offs[wid], end = offs[wid + 1];
    float sd[H], mx[H], den[H];
    #pragma unroll
    for (int h = 0; h < H; ++h) {
        sd[h] = sdst[wid * H + h];
        float t = funmap(gmaxu[h]) + sd[h];
        mx[h] = t > 0.f ? t : 0.2f * t;     // leaky is monotone
        den[h] = 0.f;
    }
    for (int i = beg + lane; i < end; i += 64) {
        int s = csr[i];
        float sv[H];
        loadS<H>(ssrc + (size_t)s * H, sv);
        #pragma unroll
        for (int h = 0; h < H; ++h) {
            float sc = sv[h] + sd[h];
            sc = sc > 0.f ? sc : 0.2f * sc;
            float w = __expf(sc - mx[h]);
            wbuf[(size_t)i * H + h] = w;
            den[h] += w;
        }
    }
    #pragma unroll
    for (int h = 0; h < H; ++h) {
        #pragma unroll
        for (int off = 32; off; off >>= 1) den[h] += __shfl_xor(den[h], off);
    }
    if (lane == 0) {
        #pragma unroll
        for (int h = 0; h < H; ++h) rden[wid * H + h] = 1.f / (den[h] + 1e-16f);
    }
}

// ===================== weighted aggregation (fp16 plane gathers) ============
// wave per node, lane = channel; H/2 uint gathers per edge per lane.
// Tail is a single predicated U-batch: padded slots reuse the last real edge's
// source (L1-hit duplicate gather) with weight 0 -> exact, no serial tail.
template<int H, bool MEAN>
__global__ __launch_bounds__(256)
void agg_kernel(const ushort_t* __restrict__ h16, const float* __restrict__ wbuf,
                const float* __restrict__ rden, const int* __restrict__ offs,
                const int* __restrict__ csr, const float* __restrict__ bias,
                float* __restrict__ outf, ushort_t* __restrict__ ohi,
                ushort_t* __restrict__ olo, int Nn) {
    constexpr int P = H / 2;
    constexpr int U = (H == 4) ? 8 : 4;
    int wid = (blockIdx.x * blockDim.x + threadIdx.x) >> 6;
    int lane = threadIdx.x & 63;
    if (wid >= Nn) return;
    int beg = offs[wid], end = offs[wid + 1];
    const uint_t* up = (const uint_t*)h16;
    const size_t psz = (size_t)Nn * 64;

    float acc0[H] = {}, acc1[H] = {};
    for (int i = beg; i < end; i += U) {
        int rem = end - i;                      // >= 1
        bool full = (rem >= U);                 // wave-uniform
        int s[U];
        #pragma unroll
        for (int j = 0; j < U; ++j) {
            int jj = full ? j : (j < rem ? j : rem - 1);
            s[j] = csr[i + jj];
        }
        uint_t g[U][P];
        #pragma unroll
        for (int j = 0; j < U; ++j)
            #pragma unroll
            for (int p = 0; p < P; ++p)
                g[j][p] = up[(size_t)p * psz + (size_t)s[j] * 64 + lane];
        float w[U][H];
        #pragma unroll
        for (int j = 0; j < U; ++j) {
            if (full || j < rem) {
                if constexpr (H == 4) {
                    float4 t = *(const float4*)&wbuf[(size_t)(i + j) * 4];
                    w[j][0] = t.x; w[j][1] = t.y; w[j][2] = t.z; w[j][3] = t.w;
                } else {
                    const float2* q = (const float2*)&wbuf[(size_t)(i + j) * 6];
                    float2 a = q[0], b = q[1], c = q[2];
                    w[j][0] = a.x; w[j][1] = a.y; w[j][2] = b.x;
                    w[j][3] = b.y; w[j][4] = c.x; w[j][5] = c.y;
                }
            } else {
                #pragma unroll
                for (int h = 0; h < H; ++h) w[j][h] = 0.f;
            }
        }
        #pragma unroll
        for (int j = 0; j < U; ++j) {
            float v[H];
            #pragma unroll
            for (int p = 0; p < P; ++p) cvt2(g[j][p], v[2 * p], v[2 * p + 1]);
            float* a = (j & 1) ? acc1 : acc0;
            #pragma unroll
            for (int h = 0; h < H; ++h) a[h] += w[j][h] * v[h];
        }
    }

    if (!MEAN) {
        #pragma unroll
        for (int h = 0; h < H; ++h) {
            float val = (acc0[h] + acc1[h]) * rden[wid * H + h] + bias[h * 64 + lane];
            val = val > 0.f ? val : expm1f(val);   // ELU
            size_t idx = (size_t)wid * (H * 64) + h * 64 + lane;
            ushort_t hb = f2bf_bits(val);
            ohi[idx] = hb;
            olo[idx] = f2bf_bits(val - bfbits2f(hb));
        }
    } else {
        float m = 0.f;
        #pragma unroll
        for (int h = 0; h < H; ++h) m += (acc0[h] + acc1[h]) * rden[wid * H + h];
        outf[(size_t)wid * 64 + lane] = m * (1.f / (float)H) + bias[lane];
    }
}

// ============================ launch ========================================
extern "C" void kernel_launch(void* const* d_in, const int* in_sizes, int n_in,
                              void* d_out, int out_size, void* d_ws, size_t ws_size,
                              hipStream_t stream) {
    const float* x     = (const float*)d_in[0];
    const int*   ei    = (const int*)d_in[1];
    const float* W1    = (const float*)d_in[2];
    const float* a1s   = (const float*)d_in[3];
    const float* a1d   = (const float*)d_in[4];
    const float* b1    = (const float*)d_in[5];
    const float* W2    = (const float*)d_in[6];
    const float* a2s   = (const float*)d_in[7];
    const float* a2d   = (const float*)d_in[8];
    const float* b2    = (const float*)d_in[9];
    const float* W3    = (const float*)d_in[10];
    const float* a3s   = (const float*)d_in[11];
    const float* a3d   = (const float*)d_in[12];
    const float* b3    = (const float*)d_in[13];
    float* out = (float*)d_out;

    const int Nn = NNODES;
    const int E  = in_sizes[1] / 2;
    const int Etot = E + Nn;

    char* p = (char*)d_ws;
    auto carve = [&](size_t bytes) {
        char* r = p;
        p += (bytes + 255) & ~(size_t)255;
        return (void*)r;
    };
    ushort_t* h16   = (ushort_t*)carve((size_t)Nn * 384 * 2);   // up to 3 planes
    ushort_t* R1    = (ushort_t*)carve((size_t)Nn * 256 * 4);
    ushort_t* x_hi  = R1;
    ushort_t* x_lo  = R1 + (size_t)Nn * 128;
    ushort_t* x1_hi = R1;
    ushort_t* x1_lo = R1 + (size_t)Nn * 256;
    ushort_t* w1hi  = (ushort_t*)carve((size_t)128 * 256 * 2);
    ushort_t* w1lo  = (ushort_t*)carve((size_t)128 * 256 * 2);
    ushort_t* w2hi  = (ushort_t*)carve((size_t)256 * 256 * 2);
    ushort_t* w2lo  = (ushort_t*)carve((size_t)256 * 256 * 2);
    ushort_t* w3hi  = (ushort_t*)carve((size_t)256 * 384 * 2);
    ushort_t* w3lo  = (ushort_t*)carve((size_t)256 * 384 * 2);
    float* ssrc   = (float*)carve((size_t)Nn * 6 * 4);
    float* sdst   = (float*)carve((size_t)Nn * 6 * 4);
    float* rden   = (float*)carve((size_t)Nn * 6 * 4);
    float* wbuf   = (float*)carve((size_t)Etot * 6 * 4);
    int*   deg    = (int*)carve((size_t)Nn * 4);
    int*   offs   = (int*)carve((size_t)(Nn + 1) * 4);
    int*   cursor = (int*)carve((size_t)Nn * 4);
    int*   csr    = (int*)carve((size_t)Etot * 4);
    uint_t* gmaxu = (uint_t*)carve(18 * 4);
    int*   bsum   = (int*)carve(64 * 4);
    int*   bexcl  = (int*)carve(64 * 4);

    // -------- CSR build --------
    hipMemsetAsync(deg, 0, (size_t)Nn * 4, stream);
    hipMemsetAsync(gmaxu, 0, 18 * 4, stream);   // 0 == fmap(-inf) lower bound
    {
        int nb = (Etot + 255) / 256;
        int nsb = (Nn + 1023) / 1024;
        deg_kernel<<<nb, 256, 0, stream>>>(ei, E, Nn, deg);
        scan1_kernel<<<nsb, 1024, 0, stream>>>(deg, offs, bsum, Nn);
        scan2_kernel<<<1, 64, 0, stream>>>(bsum, bexcl, nsb);
        scan3_kernel<<<(Nn + 255) / 256, 256, 0, stream>>>(deg, offs, bexcl, cursor, Nn);
        scatter_kernel<<<nb, 256, 0, stream>>>(ei, E, Nn, cursor, csr);
    }

    // -------- weight + input prep --------
    {
        int n4 = Nn * 128 / 4;
        split_kernel<<<(n4 + 255) / 256, 256, 0, stream>>>(
            (const float4*)x, (ushort4*)x_hi, (ushort4*)x_lo, n4);
        int wtot = 128 * 256 + 256 * 256 + 256 * 384;
        wprep_all<<<(wtot + 255) / 256, 256, 0, stream>>>(W1, W2, W3, w1hi, w1lo,
                                                          w2hi, w2lo, w3hi, w3lo);
    }

    const int node_blocks = (Nn + 3) / 4;
    const int gemm_rows = (Nn + 127) / 128;

    // -------- layer 1: [50000,128] @ [128,256], H=4, concat+ELU --------
    {
        gemm_fused<4><<<2 * gemm_rows, 256, 0, stream>>>(x_hi, x_lo, w1hi, w1lo, h16,
                                                         ssrc, sdst, gmaxu + 0, a1s, a1d,
                                                         2, Nn, 128);
        smw_kernel<4><<<node_blocks, 256, 0, stream>>>(ssrc, sdst, gmaxu + 0, offs, csr,
                                                       wbuf, rden, Nn);
        agg_kernel<4, false><<<node_blocks, 256, 0, stream>>>(h16, wbuf, rden, offs, csr, b1,
                                                              nullptr, x1_hi, x1_lo, Nn);
    }
    // -------- layer 2: [50000,256] @ [256,256], H=4, concat+ELU --------
    {
        gemm_fused<4><<<2 * gemm_rows, 256, 0, stream>>>(x1_hi, x1_lo, w2hi, w2lo, h16,
                                                         ssrc, sdst, gmaxu + 6, a2s, a2d,
                                                         2, Nn, 256);
        smw_kernel<4><<<node_blocks, 256, 0, stream>>>(ssrc, sdst, gmaxu + 6, offs, csr,
                                                       wbuf, rden, Nn);
        agg_kernel<4, false><<<node_blocks, 256, 0, stream>>>(h16, wbuf, rden, offs, csr, b2,
                                                              nullptr, x1_hi, x1_lo, Nn);
    }
    // -------- layer 3: [50000,256] @ [256,384], H=6, mean --------
    {
        gemm_fused<6><<<3 * gemm_rows, 256, 0, stream>>>(x1_hi, x1_lo, w3hi, w3lo, h16,
                                                         ssrc, sdst, gmaxu + 12, a3s, a3d,
                                                         3, Nn, 256);
        smw_kernel<6><<<node_blocks, 256, 0, stream>>>(ssrc, sdst, gmaxu + 12, offs, csr,
                                                       wbuf, rden, Nn);
        agg_kernel<6, true><<<node_blocks, 256, 0, stream>>>(h16, wbuf, rden, offs, csr, b3,
                                                             out, nullptr, nullptr, Nn);
    }
}

// Round 11
// 564.048 us; speedup vs baseline: 1.1018x; 1.0558x over previous
//
#include <hip/hip_runtime.h>
#include <hip/hip_bf16.h>
#include <hip/hip_fp16.h>
#include <math.h>

#define NNODES 50000

typedef __attribute__((ext_vector_type(8))) short short8v;
typedef __attribute__((ext_vector_type(4))) float f32x4;
typedef unsigned short ushort_t;
typedef unsigned int uint_t;

// ---------------- bf16 / fp16 helpers ----------------
__device__ inline ushort_t f2bf_bits(float v) {
    union { __hip_bfloat16 b; ushort_t u; } c;
    c.b = __float2bfloat16(v);
    return c.u;
}
__device__ inline float bfbits2f(ushort_t u) {
    union { __hip_bfloat16 b; ushort_t u; } c;
    c.u = u;
    return __bfloat162float(c.b);
}
__device__ inline ushort_t f2h_bits(float v) {
    union { __half h; ushort_t u; } c;
    c.h = __float2half(v);
    return c.u;
}
__device__ inline void cvt2(uint_t u, float& a, float& b) {
    union { uint_t u; __half2 h; } c; c.u = u;
    a = __low2float(c.h); b = __high2float(c.h);
}
// monotone float<->uint mapping (for atomicMax on floats incl. negatives)
__device__ inline uint_t fmap(float f) {
    uint_t b = __float_as_uint(f);
    return (b & 0x80000000u) ? ~b : (b | 0x80000000u);
}
__device__ inline float funmap(uint_t u) {
    return __uint_as_float((u & 0x80000000u) ? (u & 0x7FFFFFFFu) : ~u);
}

// split fp32 -> (hi, lo) bf16 pair, vectorized x4
__global__ __launch_bounds__(256)
void split_kernel(const float4* __restrict__ in, ushort4* __restrict__ hi,
                  ushort4* __restrict__ lo, int n4) {
    int i = blockIdx.x * blockDim.x + threadIdx.x;
    if (i >= n4) return;
    float4 v = in[i];
    ushort4 h, l;
    h.x = f2bf_bits(v.x); l.x = f2bf_bits(v.x - bfbits2f(h.x));
    h.y = f2bf_bits(v.y); l.y = f2bf_bits(v.y - bfbits2f(h.y));
    h.z = f2bf_bits(v.z); l.z = f2bf_bits(v.z - bfbits2f(h.z));
    h.w = f2bf_bits(v.w); l.w = f2bf_bits(v.w - bfbits2f(h.w));
    hi[i] = h; lo[i] = l;
}

// all three weight transposes/splits in one launch
__global__ __launch_bounds__(256)
void wprep_all(const float* __restrict__ W1, const float* __restrict__ W2,
               const float* __restrict__ W3,
               ushort_t* __restrict__ w1h, ushort_t* __restrict__ w1l,
               ushort_t* __restrict__ w2h, ushort_t* __restrict__ w2l,
               ushort_t* __restrict__ w3h, ushort_t* __restrict__ w3l) {
    int idx = blockIdx.x * blockDim.x + threadIdx.x;
    const float* W; ushort_t* hT; ushort_t* lT; int K, N;
    if (idx < 128 * 256) { W = W1; hT = w1h; lT = w1l; K = 128; N = 256; }
    else if (idx < 128 * 256 + 256 * 256) {
        idx -= 128 * 256; W = W2; hT = w2h; lT = w2l; K = 256; N = 256;
    } else {
        idx -= 128 * 256 + 256 * 256;
        if (idx >= 256 * 384) return;
        W = W3; hT = w3h; lT = w3l; K = 256; N = 384;
    }
    int k = idx / N, n = idx - k * N;
    float v = W[idx];
    ushort_t hb = f2bf_bits(v);
    hT[(size_t)n * K + k] = hb;
    lT[(size_t)n * K + k] = f2bf_bits(v - bfbits2f(hb));
}

// ============ fused split-bf16 3-pass MFMA GEMM + pack + score ==============
// C = A[M][K] * B[K][N] (B stored transposed [N][K], hi/lo bf16).
// BM=64, BN=128 (exactly 2 heads), BK=32; 4 waves (2x2) of 32x64 each.
// Small tile -> 2x more blocks (~6/CU) for latency hiding at low MfmaUtil.
// LDS staging k-chunk-major: conflict-free ds_read_b128 fragments.
// Epilogue: acc -> LDS fp16 (XOR-swizzled) -> head-pair plane h16[p][n][c][2],
// fused s_src/s_dst dot-reduce, per-head global max (monotone-uint atomicMax).
template<int H>
__global__ __launch_bounds__(256)
void gemm_fused(const ushort_t* __restrict__ Ahi, const ushort_t* __restrict__ Alo,
                const ushort_t* __restrict__ Bhi, const ushort_t* __restrict__ Blo,
                ushort_t* __restrict__ h16, float* __restrict__ ssrc,
                float* __restrict__ sdst, uint_t* __restrict__ gmaxu,
                const float* __restrict__ a_src, const float* __restrict__ a_dst,
                int M, int K) {
    __shared__ char smem[24576];            // staging (A 2x4KB + B 2x8KB) / h2 union
    __shared__ float sSs[64][2], sDs[64][2];
    __shared__ uint_t gblk[2];

    const int tid = threadIdx.x;
    const int lane = tid & 63;
    const int wid = tid >> 6;
    const int wm = wid >> 1, wn = wid & 1;
    const int bm = blockIdx.y * 64;
    const int bn = blockIdx.x * 128;
    const int r15 = lane & 15;
    const int g4 = lane >> 4;

    if (tid < 128) { ((float*)sSs)[tid] = 0.f; ((float*)sDs)[tid] = 0.f; }
    if (tid < 2) gblk[tid] = 0;

    char* As_hi = smem;                     // 4 chunks x 64 rows x 16B = 4KB
    char* As_lo = smem + 4096;
    char* Bs_hi = smem + 8192;              // 4 chunks x 128 rows x 16B = 8KB
    char* Bs_lo = smem + 16384;

    const int srow = tid >> 2;              // 0..63
    const int skc  = tid & 3;               // k-chunk 0..3
    // rows >= M read adjacent ws regions: valid memory, never stored (guarded)
    const size_t arow  = (size_t)(bm + srow) * K;
    const size_t brow0 = (size_t)(bn + srow) * K;
    const size_t brow1 = (size_t)(bn + 64 + srow) * K;

    f32x4 acc[2][4] = {};

    for (int k0 = 0; k0 < K; k0 += 32) {
        short8v a0 = *(const short8v*)&Ahi[arow  + k0 + skc * 8];
        short8v l0 = *(const short8v*)&Alo[arow  + k0 + skc * 8];
        short8v b0 = *(const short8v*)&Bhi[brow0 + k0 + skc * 8];
        short8v b1 = *(const short8v*)&Bhi[brow1 + k0 + skc * 8];
        short8v m0 = *(const short8v*)&Blo[brow0 + k0 + skc * 8];
        short8v m1 = *(const short8v*)&Blo[brow1 + k0 + skc * 8];
        __syncthreads();                 // previous iteration's reads done
        *(short8v*)(As_hi + skc * 1024 + srow * 16)        = a0;
        *(short8v*)(As_lo + skc * 1024 + srow * 16)        = l0;
        *(short8v*)(Bs_hi + skc * 2048 + srow * 16)        = b0;
        *(short8v*)(Bs_hi + skc * 2048 + (64 + srow) * 16) = b1;
        *(short8v*)(Bs_lo + skc * 2048 + srow * 16)        = m0;
        *(short8v*)(Bs_lo + skc * 2048 + (64 + srow) * 16) = m1;
        __syncthreads();

        short8v ah[2], al[2], bh[4], bl[4];
        #pragma unroll
        for (int mi = 0; mi < 2; ++mi) {
            int row = wm * 32 + mi * 16 + r15;
            ah[mi] = *(const short8v*)(As_hi + g4 * 1024 + row * 16);
            al[mi] = *(const short8v*)(As_lo + g4 * 1024 + row * 16);
        }
        #pragma unroll
        for (int nj = 0; nj < 4; ++nj) {
            int row = wn * 64 + nj * 16 + r15;
            bh[nj] = *(const short8v*)(Bs_hi + g4 * 2048 + row * 16);
            bl[nj] = *(const short8v*)(Bs_lo + g4 * 2048 + row * 16);
        }
        #pragma unroll
        for (int mi = 0; mi < 2; ++mi)
            #pragma unroll
            for (int nj = 0; nj < 4; ++nj) {
                acc[mi][nj] = __builtin_amdgcn_mfma_f32_16x16x32_bf16(ah[mi], bh[nj], acc[mi][nj], 0, 0, 0);
                acc[mi][nj] = __builtin_amdgcn_mfma_f32_16x16x32_bf16(ah[mi], bl[nj], acc[mi][nj], 0, 0, 0);
                acc[mi][nj] = __builtin_amdgcn_mfma_f32_16x16x32_bf16(al[mi], bh[nj], acc[mi][nj], 0, 0, 0);
            }
    }
    __syncthreads();                    // all waves done reading staging LDS

    // ---- epilogue: h2 transpose + fused scores ----
    ushort_t* h2 = (ushort_t*)smem;     // [64 rows][128 cols] fp16, col XOR-swizzle
    const int headg = (bn >> 6) + wn;   // global head of this wave's 64-col slice
    float asv[4], adv[4];
    #pragma unroll
    for (int nj = 0; nj < 4; ++nj) {
        asv[nj] = a_src[headg * 64 + nj * 16 + r15];
        adv[nj] = a_dst[headg * 64 + nj * 16 + r15];
    }
    #pragma unroll
    for (int mi = 0; mi < 2; ++mi) {
        #pragma unroll
        for (int reg = 0; reg < 4; ++reg) {
            int row_l = wm * 32 + mi * 16 + g4 * 4 + reg;     // 0..63
            int csw = ((row_l >> 2) & 3) << 2;
            float pS = 0.f, pD = 0.f;
            #pragma unroll
            for (int nj = 0; nj < 4; ++nj) {
                float v = acc[mi][nj][reg];
                int col_l = wn * 64 + nj * 16 + r15;
                h2[row_l * 128 + (col_l ^ csw)] = f2h_bits(v);
                pS += v * asv[nj];
                pD += v * adv[nj];
            }
            #pragma unroll
            for (int off = 1; off < 16; off <<= 1) {   // reduce over 16 r15 lanes
                pS += __shfl_xor(pS, off);
                pD += __shfl_xor(pD, off);
            }
            if (r15 == 0) {            // single writer per (row_l, wn)
                sSs[row_l][wn] = pS;
                sDs[row_l][wn] = pD;
            }
        }
    }
    __syncthreads();

    // h16 plane write: plane p = bn/128; per node 64 uint (=256B) contiguous
    uint_t* plane = (uint_t*)h16 + (size_t)(bn >> 7) * ((size_t)NNODES * 64);
    for (int u = tid; u < 64 * 64; u += 256) {
        int n_l = u >> 6, c = u & 63;
        if (bm + n_l < M) {
            int csw = ((n_l >> 2) & 3) << 2;
            uint_t lo = h2[n_l * 128 + (c ^ csw)];
            uint_t hi = h2[n_l * 128 + 64 + (c ^ csw)];
            plane[(size_t)(bm + n_l) * 64 + c] = lo | (hi << 16);
        }
    }
    // scores out + per-head block max
    if (tid < 128) {
        int row = tid >> 1, hl = tid & 1;
        if (bm + row < M) {
            int hg = (bn >> 6) + hl;
            float vS = sSs[row][hl];
            ssrc[(size_t)(bm + row) * H + hg] = vS;
            sdst[(size_t)(bm + row) * H + hg] = sDs[row][hl];
            atomicMax(&gblk[hl], fmap(vS));
        }
    }
    __syncthreads();
    if (tid < 2) atomicMax(&gmaxu[(bn >> 6) + tid], gblk[tid]);
}

// ============================ CSR build =====================================
__global__ void deg_kernel(const int* __restrict__ ei, int E, int Nn,
                           int* __restrict__ deg) {
    int e = blockIdx.x * blockDim.x + threadIdx.x;
    int tot = E + Nn;
    if (e >= tot) return;
    int d = (e < E) ? ei[E + e] : (e - E);
    atomicAdd(&deg[d], 1);
}

// two-level scan: (1) per-block local inclusive scan, (2) 1-wave scan of block
// sums, (3) add carries + derive cursor
__global__ __launch_bounds__(1024)
void scan1_kernel(const int* __restrict__ deg, int* __restrict__ offs,
                  int* __restrict__ bsum, int n) {
    __shared__ int sh[1024];
    int t = threadIdx.x;
    int i = blockIdx.x * 1024 + t;
    int v = (i < n) ? deg[i] : 0;
    sh[t] = v;
    __syncthreads();
    for (int off = 1; off < 1024; off <<= 1) {
        int add = (t >= off) ? sh[t - off] : 0;
        __syncthreads();
        sh[t] += add;
        __syncthreads();
    }
    if (i < n) offs[i + 1] = sh[t];
    if (t == 1023) bsum[blockIdx.x] = sh[1023];
}

__global__ __launch_bounds__(64)
void scan2_kernel(const int* __restrict__ bsum, int* __restrict__ bexcl, int nb) {
    int t = threadIdx.x;
    int v = (t < nb) ? bsum[t] : 0;
    int orig = v;
    #pragma unroll
    for (int off = 1; off < 64; off <<= 1) {
        int u = __shfl_up(v, off);
        if (t >= off) v += u;
    }
    if (t < nb) bexcl[t] = v - orig;
}

__global__ void scan3_kernel(const int* __restrict__ deg, int* __restrict__ offs,
                             const int* __restrict__ bexcl, int* __restrict__ cursor,
                             int n) {
    int i = blockIdx.x * blockDim.x + threadIdx.x;
    if (i == 0) offs[0] = 0;
    if (i < n) {
        int inc = offs[i + 1] + bexcl[i >> 10];
        offs[i + 1] = inc;
        cursor[i] = inc - deg[i];
    }
}

__global__ void scatter_kernel(const int* __restrict__ ei, int E, int Nn,
                               int* __restrict__ cursor, int* __restrict__ csr_src) {
    int e = blockIdx.x * blockDim.x + threadIdx.x;
    int tot = E + Nn;
    if (e >= tot) return;
    int s, d;
    if (e < E) { s = ei[e]; d = ei[E + e]; }
    else       { s = d = e - E; }
    int pos = atomicAdd(&cursor[d], 1);
    csr_src[pos] = s;
}

// ---------------- vector load of ssrc row [H floats] ----------------
template<int H>
__device__ inline void loadS(const float* __restrict__ p, float* v) {
    if constexpr (H == 4) {
        float4 t = *(const float4*)p;
        v[0] = t.x; v[1] = t.y; v[2] = t.z; v[3] = t.w;
    } else {
        const float2* q = (const float2*)p;
        float2 a = q[0], b = q[1], c = q[2];
        v[0] = a.x; v[1] = a.y; v[2] = b.x; v[3] = b.y; v[4] = c.x; v[5] = c.y;
    }
}

// ==== single-pass: edge weights + recip denominator (global-max shift) ======
// m_d = leaky(gmax_h + sdst_d) >= max_e leaky(ssrc_e + sdst_d), exponent <= 0;
// per-destination shift cancels in alpha = w/den, so result is exact up to fp.
template<int H>
__global__ __launch_bounds__(256)
void smw_kernel(const float* __restrict__ ssrc, const float* __restrict__ sdst,
                const uint_t* __restrict__ gmaxu, const int* __restrict__ offs,
                const int* __restrict__ csr, float* __restrict__ wbuf,
                float* __restrict__ rden, int Nn) {
    int wid = (blockIdx.x * blockDim.x + threadIdx.x) >> 6;
    int lane = threadIdx.x & 63;
    if (wid >= Nn) return;
    int beg = offs[wid], end = offs[wid + 1];
    float sd[H], mx[H], den[H];
    #pragma unroll
    for (int h = 0; h < H; ++h) {
        sd[h] = sdst[wid * H + h];
        float t = funmap(gmaxu[h]) + sd[h];
        mx[h] = t > 0.f ? t : 0.2f * t;     // leaky is monotone
        den[h] = 0.f;
    }
    for (int i = beg + lane; i < end; i += 64) {
        int s = csr[i];
        float sv[H];
        loadS<H>(ssrc + (size_t)s * H, sv);
        #pragma unroll
        for (int h = 0; h < H; ++h) {
            float sc = sv[h] + sd[h];
            sc = sc > 0.f ? sc : 0.2f * sc;
            float w = __expf(sc - mx[h]);
            wbuf[(size_t)i * H + h] = w;
            den[h] += w;
        }
    }
    #pragma unroll
    for (int h = 0; h < H; ++h) {
        #pragma unroll
        for (int off = 32; off; off >>= 1) den[h] += __shfl_xor(den[h], off);
    }
    if (lane == 0) {
        #pragma unroll
        for (int h = 0; h < H; ++h) rden[wid * H + h] = 1.f / (den[h] + 1e-16f);
    }
}

// ===================== weighted aggregation (fp16 plane gathers) ============
// wave per node, lane = channel; H/2 uint gathers per edge per lane
// (plane p holds heads 2p, 2p+1 interleaved: dense 256B run per node per plane).
template<int H, bool MEAN>
__global__ __launch_bounds__(256)
void agg_kernel(const ushort_t* __restrict__ h16, const float* __restrict__ wbuf,
                const float* __restrict__ rden, const int* __restrict__ offs,
                const int* __restrict__ csr, const float* __restrict__ bias,
                float* __restrict__ outf, ushort_t* __restrict__ ohi,
                ushort_t* __restrict__ olo, int Nn) {
    constexpr int P = H / 2;
    int wid = (blockIdx.x * blockDim.x + threadIdx.x) >> 6;
    int lane = threadIdx.x & 63;
    if (wid >= Nn) return;
    int beg = offs[wid], end = offs[wid + 1];
    const uint_t* up = (const uint_t*)h16;
    const size_t psz = (size_t)Nn * 64;

    constexpr int U = (H == 4) ? 8 : 4;
    float acc0[H] = {}, acc1[H] = {};
    int i = beg;
    for (; i + U <= end; i += U) {
        int s[U];
        #pragma unroll
        for (int j = 0; j < U; ++j) s[j] = csr[i + j];
        uint_t g[U][P];
        #pragma unroll
        for (int j = 0; j < U; ++j)
            #pragma unroll
            for (int p = 0; p < P; ++p)
                g[j][p] = up[(size_t)p * psz + (size_t)s[j] * 64 + lane];
        float w[U][H];
        #pragma unroll
        for (int j = 0; j < U; ++j) {
            if constexpr (H == 4) {
                float4 t = *(const float4*)&wbuf[(size_t)(i + j) * 4];
                w[j][0] = t.x; w[j][1] = t.y; w[j][2] = t.z; w[j][3] = t.w;
            } else {
                const float2* q = (const float2*)&wbuf[(size_t)(i + j) * 6];
                float2 a = q[0], b = q[1], c = q[2];
                w[j][0] = a.x; w[j][1] = a.y; w[j][2] = b.x;
                w[j][3] = b.y; w[j][4] = c.x; w[j][5] = c.y;
            }
        }
        #pragma unroll
        for (int j = 0; j < U; ++j) {
            float v[H];
            #pragma unroll
            for (int p = 0; p < P; ++p) cvt2(g[j][p], v[2 * p], v[2 * p + 1]);
            float* a = (j & 1) ? acc1 : acc0;
            #pragma unroll
            for (int h = 0; h < H; ++h) a[h] += w[j][h] * v[h];
        }
    }
    for (; i < end; ++i) {
        int s = csr[i];
        float v[H];
        #pragma unroll
        for (int p = 0; p < P; ++p) {
            uint_t g = up[(size_t)p * psz + (size_t)s * 64 + lane];
            cvt2(g, v[2 * p], v[2 * p + 1]);
        }
        #pragma unroll
        for (int h = 0; h < H; ++h) acc0[h] += wbuf[(size_t)i * H + h] * v[h];
    }

    if (!MEAN) {
        #pragma unroll
        for (int h = 0; h < H; ++h) {
            float val = (acc0[h] + acc1[h]) * rden[wid * H + h] + bias[h * 64 + lane];
            val = val > 0.f ? val : expm1f(val);   // ELU
            size_t idx = (size_t)wid * (H * 64) + h * 64 + lane;
            ushort_t hb = f2bf_bits(val);
            ohi[idx] = hb;
            olo[idx] = f2bf_bits(val - bfbits2f(hb));
        }
    } else {
        float m = 0.f;
        #pragma unroll
        for (int h = 0; h < H; ++h) m += (acc0[h] + acc1[h]) * rden[wid * H + h];
        outf[(size_t)wid * 64 + lane] = m * (1.f / (float)H) + bias[lane];
    }
}

// ============================ launch ========================================
extern "C" void kernel_launch(void* const* d_in, const int* in_sizes, int n_in,
                              void* d_out, int out_size, void* d_ws, size_t ws_size,
                              hipStream_t stream) {
    const float* x     = (const float*)d_in[0];
    const int*   ei    = (const int*)d_in[1];
    const float* W1    = (const float*)d_in[2];
    const float* a1s   = (const float*)d_in[3];
    const float* a1d   = (const float*)d_in[4];
    const float* b1    = (const float*)d_in[5];
    const float* W2    = (const float*)d_in[6];
    const float* a2s   = (const float*)d_in[7];
    const float* a2d   = (const float*)d_in[8];
    const float* b2    = (const float*)d_in[9];
    const float* W3    = (const float*)d_in[10];
    const float* a3s   = (const float*)d_in[11];
    const float* a3d   = (const float*)d_in[12];
    const float* b3    = (const float*)d_in[13];
    float* out = (float*)d_out;

    const int Nn = NNODES;
    const int E  = in_sizes[1] / 2;
    const int Etot = E + Nn;

    char* p = (char*)d_ws;
    auto carve = [&](size_t bytes) {
        char* r = p;
        p += (bytes + 255) & ~(size_t)255;
        return (void*)r;
    };
    ushort_t* h16   = (ushort_t*)carve((size_t)Nn * 384 * 2);   // up to 3 planes
    ushort_t* R1    = (ushort_t*)carve((size_t)Nn * 256 * 4);
    ushort_t* x_hi  = R1;
    ushort_t* x_lo  = R1 + (size_t)Nn * 128;
    ushort_t* x1_hi = R1;
    ushort_t* x1_lo = R1 + (size_t)Nn * 256;
    ushort_t* w1hi  = (ushort_t*)carve((size_t)128 * 256 * 2);
    ushort_t* w1lo  = (ushort_t*)carve((size_t)128 * 256 * 2);
    ushort_t* w2hi  = (ushort_t*)carve((size_t)256 * 256 * 2);
    ushort_t* w2lo  = (ushort_t*)carve((size_t)256 * 256 * 2);
    ushort_t* w3hi  = (ushort_t*)carve((size_t)256 * 384 * 2);
    ushort_t* w3lo  = (ushort_t*)carve((size_t)256 * 384 * 2);
    float* ssrc   = (float*)carve((size_t)Nn * 6 * 4);
    float* sdst   = (float*)carve((size_t)Nn * 6 * 4);
    float* rden   = (float*)carve((size_t)Nn * 6 * 4);
    float* wbuf   = (float*)carve((size_t)Etot * 6 * 4);
    int*   deg    = (int*)carve((size_t)Nn * 4);
    int*   offs   = (int*)carve((size_t)(Nn + 1) * 4);
    int*   cursor = (int*)carve((size_t)Nn * 4);
    int*   csr    = (int*)carve((size_t)Etot * 4);
    uint_t* gmaxu = (uint_t*)carve(18 * 4);
    int*   bsum   = (int*)carve(64 * 4);
    int*   bexcl  = (int*)carve(64 * 4);

    // -------- CSR build --------
    hipMemsetAsync(deg, 0, (size_t)Nn * 4, stream);
    hipMemsetAsync(gmaxu, 0, 18 * 4, stream);   // 0 == fmap(-inf) lower bound
    {
        int nb = (Etot + 255) / 256;
        int nsb = (Nn + 1023) / 1024;
        deg_kernel<<<nb, 256, 0, stream>>>(ei, E, Nn, deg);
        scan1_kernel<<<nsb, 1024, 0, stream>>>(deg, offs, bsum, Nn);
        scan2_kernel<<<1, 64, 0, stream>>>(bsum, bexcl, nsb);
        scan3_kernel<<<(Nn + 255) / 256, 256, 0, stream>>>(deg, offs, bexcl, cursor, Nn);
        scatter_kernel<<<nb, 256, 0, stream>>>(ei, E, Nn, cursor, csr);
    }

    // -------- weight + input prep --------
    {
        int n4 = Nn * 128 / 4;
        split_kernel<<<(n4 + 255) / 256, 256, 0, stream>>>(
            (const float4*)x, (ushort4*)x_hi, (ushort4*)x_lo, n4);
        int wtot = 128 * 256 + 256 * 256 + 256 * 384;
        wprep_all<<<(wtot + 255) / 256, 256, 0, stream>>>(W1, W2, W3, w1hi, w1lo,
                                                          w2hi, w2lo, w3hi, w3lo);
    }

    const int node_blocks = (Nn + 3) / 4;
    const int gemm_rows = (Nn + 63) / 64;

    // -------- layer 1: [50000,128] @ [128,256], H=4, concat+ELU --------
    {
        dim3 g(2, gemm_rows);
        gemm_fused<4><<<g, 256, 0, stream>>>(x_hi, x_lo, w1hi, w1lo, h16,
                                             ssrc, sdst, gmaxu + 0, a1s, a1d, Nn, 128);
        smw_kernel<4><<<node_blocks, 256, 0, stream>>>(ssrc, sdst, gmaxu + 0, offs, csr,
                                                       wbuf, rden, Nn);
        agg_kernel<4, false><<<node_blocks, 256, 0, stream>>>(h16, wbuf, rden, offs, csr, b1,
                                                              nullptr, x1_hi, x1_lo, Nn);
    }
    // -------- layer 2: [50000,256] @ [256,256], H=4, concat+ELU --------
    {
        dim3 g(2, gemm_rows);
        gemm_fused<4><<<g, 256, 0, stream>>>(x1_hi, x1_lo, w2hi, w2lo, h16,
                                             ssrc, sdst, gmaxu + 6, a2s, a2d, Nn, 256);
        smw_kernel<4><<<node_blocks, 256, 0, stream>>>(ssrc, sdst, gmaxu + 6, offs, csr,
                                                       wbuf, rden, Nn);
        agg_kernel<4, false><<<node_blocks, 256, 0, stream>>>(h16, wbuf, rden, offs, csr, b2,
                                                              nullptr, x1_hi, x1_lo, Nn);
    }
    // -------- layer 3: [50000,256] @ [256,384], H=6, mean --------
    {
        dim3 g(3, gemm_rows);
        gemm_fused<6><<<g, 256, 0, stream>>>(x1_hi, x1_lo, w3hi, w3lo, h16,
                                             ssrc, sdst, gmaxu + 12, a3s, a3d, Nn, 256);
        smw_kernel<6><<<node_blocks, 256, 0, stream>>>(ssrc, sdst, gmaxu + 12, offs, csr,
                                                       wbuf, rden, Nn);
        agg_kernel<6, true><<<node_blocks, 256, 0, stream>>>(h16, wbuf, rden, offs, csr, b3,
                                                             out, nullptr, nullptr, Nn);
    }
}

// Round 12
// 543.062 us; speedup vs baseline: 1.1444x; 1.0386x over previous
//
#include <hip/hip_runtime.h>
#include <hip/hip_bf16.h>
#include <hip/hip_fp16.h>
#include <math.h>

#define NNODES 50000

typedef __attribute__((ext_vector_type(8))) short short8v;
typedef __attribute__((ext_vector_type(4))) float f32x4;
typedef unsigned short ushort_t;
typedef unsigned int uint_t;

// ---------------- bf16 / fp16 helpers ----------------
__device__ inline ushort_t f2bf_bits(float v) {
    union { __hip_bfloat16 b; ushort_t u; } c;
    c.b = __float2bfloat16(v);
    return c.u;
}
__device__ inline float bfbits2f(ushort_t u) {
    union { __hip_bfloat16 b; ushort_t u; } c;
    c.u = u;
    return __bfloat162float(c.b);
}
__device__ inline ushort_t f2h_bits(float v) {
    union { __half h; ushort_t u; } c;
    c.h = __float2half(v);
    return c.u;
}
__device__ inline void cvt2(uint_t u, float& a, float& b) {
    union { uint_t u; __half2 h; } c; c.u = u;
    a = __low2float(c.h); b = __high2float(c.h);
}
// monotone float<->uint mapping (for atomicMax on floats incl. negatives)
__device__ inline uint_t fmap(float f) {
    uint_t b = __float_as_uint(f);
    return (b & 0x80000000u) ? ~b : (b | 0x80000000u);
}
__device__ inline float funmap(uint_t u) {
    return __uint_as_float((u & 0x80000000u) ? (u & 0x7FFFFFFFu) : ~u);
}

// split fp32 -> (hi, lo) bf16 pair, vectorized x4
__global__ __launch_bounds__(256)
void split_kernel(const float4* __restrict__ in, ushort4* __restrict__ hi,
                  ushort4* __restrict__ lo, int n4) {
    int i = blockIdx.x * blockDim.x + threadIdx.x;
    if (i >= n4) return;
    float4 v = in[i];
    ushort4 h, l;
    h.x = f2bf_bits(v.x); l.x = f2bf_bits(v.x - bfbits2f(h.x));
    h.y = f2bf_bits(v.y); l.y = f2bf_bits(v.y - bfbits2f(h.y));
    h.z = f2bf_bits(v.z); l.z = f2bf_bits(v.z - bfbits2f(h.z));
    h.w = f2bf_bits(v.w); l.w = f2bf_bits(v.w - bfbits2f(h.w));
    hi[i] = h; lo[i] = l;
}

// all three weight transposes/splits in one launch
__global__ __launch_bounds__(256)
void wprep_all(const float* __restrict__ W1, const float* __restrict__ W2,
               const float* __restrict__ W3,
               ushort_t* __restrict__ w1h, ushort_t* __restrict__ w1l,
               ushort_t* __restrict__ w2h, ushort_t* __restrict__ w2l,
               ushort_t* __restrict__ w3h, ushort_t* __restrict__ w3l) {
    int idx = blockIdx.x * blockDim.x + threadIdx.x;
    const float* W; ushort_t* hT; ushort_t* lT; int K, N;
    if (idx < 128 * 256) { W = W1; hT = w1h; lT = w1l; K = 128; N = 256; }
    else if (idx < 128 * 256 + 256 * 256) {
        idx -= 128 * 256; W = W2; hT = w2h; lT = w2l; K = 256; N = 256;
    } else {
        idx -= 128 * 256 + 256 * 256;
        if (idx >= 256 * 384) return;
        W = W3; hT = w3h; lT = w3l; K = 256; N = 384;
    }
    int k = idx / N, n = idx - k * N;
    float v = W[idx];
    ushort_t hb = f2bf_bits(v);
    hT[(size_t)n * K + k] = hb;
    lT[(size_t)n * K + k] = f2bf_bits(v - bfbits2f(hb));
}

// ============ fused split-bf16 3-pass MFMA GEMM + pack + score ==============
// C = A[M][K] * B[K][N] (B stored transposed [N][K], hi/lo bf16).
// BM=64, BN=128 (exactly 2 heads), BK=32; 4 waves (2x2) of 32x64 each.
// LDS staging k-chunk-major: conflict-free ds_read_b128 fragments.
// Epilogue: acc -> LDS fp16 (XOR-swizzled) -> head-pair plane h16[p][n][c][2],
// fused s_src/s_dst dot-reduce, per-head global max (monotone-uint atomicMax).
template<int H>
__global__ __launch_bounds__(256)
void gemm_fused(const ushort_t* __restrict__ Ahi, const ushort_t* __restrict__ Alo,
                const ushort_t* __restrict__ Bhi, const ushort_t* __restrict__ Blo,
                ushort_t* __restrict__ h16, float* __restrict__ ssrc,
                float* __restrict__ sdst, uint_t* __restrict__ gmaxu,
                const float* __restrict__ a_src, const float* __restrict__ a_dst,
                int M, int K) {
    __shared__ char smem[24576];            // staging (A 2x4KB + B 2x8KB) / h2 union
    __shared__ float sSs[64][2], sDs[64][2];
    __shared__ uint_t gblk[2];

    const int tid = threadIdx.x;
    const int lane = tid & 63;
    const int wid = tid >> 6;
    const int wm = wid >> 1, wn = wid & 1;
    const int bm = blockIdx.y * 64;
    const int bn = blockIdx.x * 128;
    const int r15 = lane & 15;
    const int g4 = lane >> 4;

    if (tid < 128) { ((float*)sSs)[tid] = 0.f; ((float*)sDs)[tid] = 0.f; }
    if (tid < 2) gblk[tid] = 0;

    char* As_hi = smem;                     // 4 chunks x 64 rows x 16B = 4KB
    char* As_lo = smem + 4096;
    char* Bs_hi = smem + 8192;              // 4 chunks x 128 rows x 16B = 8KB
    char* Bs_lo = smem + 16384;

    const int srow = tid >> 2;              // 0..63
    const int skc  = tid & 3;               // k-chunk 0..3
    // rows >= M read adjacent ws regions: valid memory, never stored (guarded)
    const size_t arow  = (size_t)(bm + srow) * K;
    const size_t brow0 = (size_t)(bn + srow) * K;
    const size_t brow1 = (size_t)(bn + 64 + srow) * K;

    f32x4 acc[2][4] = {};

    for (int k0 = 0; k0 < K; k0 += 32) {
        short8v a0 = *(const short8v*)&Ahi[arow  + k0 + skc * 8];
        short8v l0 = *(const short8v*)&Alo[arow  + k0 + skc * 8];
        short8v b0 = *(const short8v*)&Bhi[brow0 + k0 + skc * 8];
        short8v b1 = *(const short8v*)&Bhi[brow1 + k0 + skc * 8];
        short8v m0 = *(const short8v*)&Blo[brow0 + k0 + skc * 8];
        short8v m1 = *(const short8v*)&Blo[brow1 + k0 + skc * 8];
        __syncthreads();                 // previous iteration's reads done
        *(short8v*)(As_hi + skc * 1024 + srow * 16)        = a0;
        *(short8v*)(As_lo + skc * 1024 + srow * 16)        = l0;
        *(short8v*)(Bs_hi + skc * 2048 + srow * 16)        = b0;
        *(short8v*)(Bs_hi + skc * 2048 + (64 + srow) * 16) = b1;
        *(short8v*)(Bs_lo + skc * 2048 + srow * 16)        = m0;
        *(short8v*)(Bs_lo + skc * 2048 + (64 + srow) * 16) = m1;
        __syncthreads();

        short8v ah[2], al[2], bh[4], bl[4];
        #pragma unroll
        for (int mi = 0; mi < 2; ++mi) {
            int row = wm * 32 + mi * 16 + r15;
            ah[mi] = *(const short8v*)(As_hi + g4 * 1024 + row * 16);
            al[mi] = *(const short8v*)(As_lo + g4 * 1024 + row * 16);
        }
        #pragma unroll
        for (int nj = 0; nj < 4; ++nj) {
            int row = wn * 64 + nj * 16 + r15;
            bh[nj] = *(const short8v*)(Bs_hi + g4 * 2048 + row * 16);
            bl[nj] = *(const short8v*)(Bs_lo + g4 * 2048 + row * 16);
        }
        #pragma unroll
        for (int mi = 0; mi < 2; ++mi)
            #pragma unroll
            for (int nj = 0; nj < 4; ++nj) {
                acc[mi][nj] = __builtin_amdgcn_mfma_f32_16x16x32_bf16(ah[mi], bh[nj], acc[mi][nj], 0, 0, 0);
                acc[mi][nj] = __builtin_amdgcn_mfma_f32_16x16x32_bf16(ah[mi], bl[nj], acc[mi][nj], 0, 0, 0);
                acc[mi][nj] = __builtin_amdgcn_mfma_f32_16x16x32_bf16(al[mi], bh[nj], acc[mi][nj], 0, 0, 0);
            }
    }
    __syncthreads();                    // all waves done reading staging LDS

    // ---- epilogue: h2 transpose + fused scores ----
    ushort_t* h2 = (ushort_t*)smem;     // [64 rows][128 cols] fp16, col XOR-swizzle
    const int headg = (bn >> 6) + wn;   // global head of this wave's 64-col slice
    float asv[4], adv[4];
    #pragma unroll
    for (int nj = 0; nj < 4; ++nj) {
        asv[nj] = a_src[headg * 64 + nj * 16 + r15];
        adv[nj] = a_dst[headg * 64 + nj * 16 + r15];
    }
    #pragma unroll
    for (int mi = 0; mi < 2; ++mi) {
        #pragma unroll
        for (int reg = 0; reg < 4; ++reg) {
            int row_l = wm * 32 + mi * 16 + g4 * 4 + reg;     // 0..63
            int csw = ((row_l >> 2) & 3) << 2;
            float pS = 0.f, pD = 0.f;
            #pragma unroll
            for (int nj = 0; nj < 4; ++nj) {
                float v = acc[mi][nj][reg];
                int col_l = wn * 64 + nj * 16 + r15;
                h2[row_l * 128 + (col_l ^ csw)] = f2h_bits(v);
                pS += v * asv[nj];
                pD += v * adv[nj];
            }
            #pragma unroll
            for (int off = 1; off < 16; off <<= 1) {   // reduce over 16 r15 lanes
                pS += __shfl_xor(pS, off);
                pD += __shfl_xor(pD, off);
            }
            if (r15 == 0) {            // single writer per (row_l, wn)
                sSs[row_l][wn] = pS;
                sDs[row_l][wn] = pD;
            }
        }
    }
    __syncthreads();

    // h16 plane write: plane p = bn/128; per node 64 uint (=256B) contiguous
    uint_t* plane = (uint_t*)h16 + (size_t)(bn >> 7) * ((size_t)NNODES * 64);
    for (int u = tid; u < 64 * 64; u += 256) {
        int n_l = u >> 6, c = u & 63;
        if (bm + n_l < M) {
            int csw = ((n_l >> 2) & 3) << 2;
            uint_t lo = h2[n_l * 128 + (c ^ csw)];
            uint_t hi = h2[n_l * 128 + 64 + (c ^ csw)];
            plane[(size_t)(bm + n_l) * 64 + c] = lo | (hi << 16);
        }
    }
    // scores out + per-head block max
    if (tid < 128) {
        int row = tid >> 1, hl = tid & 1;
        if (bm + row < M) {
            int hg = (bn >> 6) + hl;
            float vS = sSs[row][hl];
            ssrc[(size_t)(bm + row) * H + hg] = vS;
            sdst[(size_t)(bm + row) * H + hg] = sDs[row][hl];
            atomicMax(&gblk[hl], fmap(vS));
        }
    }
    __syncthreads();
    if (tid < 2) atomicMax(&gmaxu[(bn >> 6) + tid], gblk[tid]);
}

// ============================ CSR build =====================================
__global__ void deg_kernel(const int* __restrict__ ei, int E, int Nn,
                           int* __restrict__ deg) {
    int e = blockIdx.x * blockDim.x + threadIdx.x;
    int tot = E + Nn;
    if (e >= tot) return;
    int d = (e < E) ? ei[E + e] : (e - E);
    atomicAdd(&deg[d], 1);
}

// two-level scan: (1) per-block local inclusive scan, (2) 1-wave scan of block
// sums, (3) add carries + derive cursor
__global__ __launch_bounds__(1024)
void scan1_kernel(const int* __restrict__ deg, int* __restrict__ offs,
                  int* __restrict__ bsum, int n) {
    __shared__ int sh[1024];
    int t = threadIdx.x;
    int i = blockIdx.x * 1024 + t;
    int v = (i < n) ? deg[i] : 0;
    sh[t] = v;
    __syncthreads();
    for (int off = 1; off < 1024; off <<= 1) {
        int add = (t >= off) ? sh[t - off] : 0;
        __syncthreads();
        sh[t] += add;
        __syncthreads();
    }
    if (i < n) offs[i + 1] = sh[t];
    if (t == 1023) bsum[blockIdx.x] = sh[1023];
}

__global__ __launch_bounds__(64)
void scan2_kernel(const int* __restrict__ bsum, int* __restrict__ bexcl, int nb) {
    int t = threadIdx.x;
    int v = (t < nb) ? bsum[t] : 0;
    int orig = v;
    #pragma unroll
    for (int off = 1; off < 64; off <<= 1) {
        int u = __shfl_up(v, off);
        if (t >= off) v += u;
    }
    if (t < nb) bexcl[t] = v - orig;
}

__global__ void scan3_kernel(const int* __restrict__ deg, int* __restrict__ offs,
                             const int* __restrict__ bexcl, int* __restrict__ cursor,
                             int n) {
    int i = blockIdx.x * blockDim.x + threadIdx.x;
    if (i == 0) offs[0] = 0;
    if (i < n) {
        int inc = offs[i + 1] + bexcl[i >> 10];
        offs[i + 1] = inc;
        cursor[i] = inc - deg[i];
    }
}

__global__ void scatter_kernel(const int* __restrict__ ei, int E, int Nn,
                               int* __restrict__ cursor, int* __restrict__ csr_src) {
    int e = blockIdx.x * blockDim.x + threadIdx.x;
    int tot = E + Nn;
    if (e >= tot) return;
    int s, d;
    if (e < E) { s = ei[e]; d = ei[E + e]; }
    else       { s = d = e - E; }
    int pos = atomicAdd(&cursor[d], 1);
    csr_src[pos] = s;
}

// ---------------- vector load of ssrc row [H floats] ----------------
template<int H>
__device__ inline void loadS(const float* __restrict__ p, float* v) {
    if constexpr (H == 4) {
        float4 t = *(const float4*)p;
        v[0] = t.x; v[1] = t.y; v[2] = t.z; v[3] = t.w;
    } else {
        const float2* q = (const float2*)p;
        float2 a = q[0], b = q[1], c = q[2];
        v[0] = a.x; v[1] = a.y; v[2] = b.x; v[3] = b.y; v[4] = c.x; v[5] = c.y;
    }
}

// ====== fused aggregation: smw folded in via per-chunk lane=edge phase ======
// wave per node. Per 64-edge chunk:
//   phase 1 (lane = edge): gather ssrc[csr[...]], compute the H weights ONCE
//     per edge (global-max shift), keep in registers, accumulate partial den.
//   phase 2 (lane = channel): U-unrolled fp16 plane gathers with
//     w = __shfl(wreg, j), s = __shfl(sreg, j) register broadcasts.
// No wbuf/rden traffic, no redundant exps. den reduced once at the end
// (identical summation order to the old smw).
template<int H, bool MEAN>
__global__ __launch_bounds__(256)
void agg_kernel(const ushort_t* __restrict__ h16, const float* __restrict__ ssrc,
                const float* __restrict__ sdst, const uint_t* __restrict__ gmaxu,
                const int* __restrict__ offs, const int* __restrict__ csr,
                const float* __restrict__ bias, float* __restrict__ outf,
                ushort_t* __restrict__ ohi, ushort_t* __restrict__ olo, int Nn) {
    constexpr int P = H / 2;
    constexpr int U = (H == 4) ? 8 : 4;
    int wid = (blockIdx.x * blockDim.x + threadIdx.x) >> 6;
    int lane = threadIdx.x & 63;
    if (wid >= Nn) return;
    int beg = offs[wid], end = offs[wid + 1];
    const uint_t* up = (const uint_t*)h16;
    const size_t psz = (size_t)Nn * 64;

    float sd[H], mx[H], den[H];
    #pragma unroll
    for (int h = 0; h < H; ++h) {
        sd[h] = sdst[wid * H + h];
        float t = funmap(gmaxu[h]) + sd[h];
        mx[h] = t > 0.f ? t : 0.2f * t;     // leaky monotone: >= all edge scores
        den[h] = 0.f;
    }

    float acc0[H] = {}, acc1[H] = {};
    for (int cbeg = beg; cbeg < end; cbeg += 64) {
        int cdeg = end - cbeg; if (cdeg > 64) cdeg = 64;
        // ---- phase 1: lane = edge ----
        float wreg[H];
        int sreg = 0;
        #pragma unroll
        for (int h = 0; h < H; ++h) wreg[h] = 0.f;
        if (lane < cdeg) {
            sreg = csr[cbeg + lane];
            float sv[H];
            loadS<H>(ssrc + (size_t)sreg * H, sv);
            #pragma unroll
            for (int h = 0; h < H; ++h) {
                float sc = sv[h] + sd[h];
                sc = sc > 0.f ? sc : 0.2f * sc;
                float w = __expf(sc - mx[h]);
                wreg[h] = w;
                den[h] += w;
            }
        }
        // ---- phase 2: lane = channel ----
        int i = 0;
        for (; i + U <= cdeg; i += U) {
            int s[U];
            #pragma unroll
            for (int j = 0; j < U; ++j) s[j] = __shfl(sreg, i + j);
            uint_t g[U][P];
            #pragma unroll
            for (int j = 0; j < U; ++j)
                #pragma unroll
                for (int p = 0; p < P; ++p)
                    g[j][p] = up[(size_t)p * psz + (size_t)s[j] * 64 + lane];
            float w[U][H];
            #pragma unroll
            for (int j = 0; j < U; ++j)
                #pragma unroll
                for (int h = 0; h < H; ++h) w[j][h] = __shfl(wreg[h], i + j);
            #pragma unroll
            for (int j = 0; j < U; ++j) {
                float v[H];
                #pragma unroll
                for (int p = 0; p < P; ++p) cvt2(g[j][p], v[2 * p], v[2 * p + 1]);
                float* a = (j & 1) ? acc1 : acc0;
                #pragma unroll
                for (int h = 0; h < H; ++h) a[h] += w[j][h] * v[h];
            }
        }
        for (; i < cdeg; ++i) {
            int s = __shfl(sreg, i);
            float v[H];
            #pragma unroll
            for (int p = 0; p < P; ++p) {
                uint_t g = up[(size_t)p * psz + (size_t)s * 64 + lane];
                cvt2(g, v[2 * p], v[2 * p + 1]);
            }
            #pragma unroll
            for (int h = 0; h < H; ++h) acc0[h] += __shfl(wreg[h], i) * v[h];
        }
    }

    // reduce den across lanes (same order as old smw)
    #pragma unroll
    for (int h = 0; h < H; ++h) {
        #pragma unroll
        for (int off = 32; off; off >>= 1) den[h] += __shfl_xor(den[h], off);
    }

    if (!MEAN) {
        #pragma unroll
        for (int h = 0; h < H; ++h) {
            float val = (acc0[h] + acc1[h]) / (den[h] + 1e-16f) + bias[h * 64 + lane];
            val = val > 0.f ? val : expm1f(val);   // ELU
            size_t idx = (size_t)wid * (H * 64) + h * 64 + lane;
            ushort_t hb = f2bf_bits(val);
            ohi[idx] = hb;
            olo[idx] = f2bf_bits(val - bfbits2f(hb));
        }
    } else {
        float m = 0.f;
        #pragma unroll
        for (int h = 0; h < H; ++h)
            m += (acc0[h] + acc1[h]) / (den[h] + 1e-16f);
        outf[(size_t)wid * 64 + lane] = m * (1.f / (float)H) + bias[lane];
    }
}

// ============================ launch ========================================
extern "C" void kernel_launch(void* const* d_in, const int* in_sizes, int n_in,
                              void* d_out, int out_size, void* d_ws, size_t ws_size,
                              hipStream_t stream) {
    const float* x     = (const float*)d_in[0];
    const int*   ei    = (const int*)d_in[1];
    const float* W1    = (const float*)d_in[2];
    const float* a1s   = (const float*)d_in[3];
    const float* a1d   = (const float*)d_in[4];
    const float* b1    = (const float*)d_in[5];
    const float* W2    = (const float*)d_in[6];
    const float* a2s   = (const float*)d_in[7];
    const float* a2d   = (const float*)d_in[8];
    const float* b2    = (const float*)d_in[9];
    const float* W3    = (const float*)d_in[10];
    const float* a3s   = (const float*)d_in[11];
    const float* a3d   = (const float*)d_in[12];
    const float* b3    = (const float*)d_in[13];
    float* out = (float*)d_out;

    const int Nn = NNODES;
    const int E  = in_sizes[1] / 2;
    const int Etot = E + Nn;

    char* p = (char*)d_ws;
    auto carve = [&](size_t bytes) {
        char* r = p;
        p += (bytes + 255) & ~(size_t)255;
        return (void*)r;
    };
    ushort_t* h16   = (ushort_t*)carve((size_t)Nn * 384 * 2);   // up to 3 planes
    ushort_t* R1    = (ushort_t*)carve((size_t)Nn * 256 * 4);
    ushort_t* x_hi  = R1;
    ushort_t* x_lo  = R1 + (size_t)Nn * 128;
    ushort_t* x1_hi = R1;
    ushort_t* x1_lo = R1 + (size_t)Nn * 256;
    ushort_t* w1hi  = (ushort_t*)carve((size_t)128 * 256 * 2);
    ushort_t* w1lo  = (ushort_t*)carve((size_t)128 * 256 * 2);
    ushort_t* w2hi  = (ushort_t*)carve((size_t)256 * 256 * 2);
    ushort_t* w2lo  = (ushort_t*)carve((size_t)256 * 256 * 2);
    ushort_t* w3hi  = (ushort_t*)carve((size_t)256 * 384 * 2);
    ushort_t* w3lo  = (ushort_t*)carve((size_t)256 * 384 * 2);
    float* ssrc   = (float*)carve((size_t)Nn * 6 * 4);
    float* sdst   = (float*)carve((size_t)Nn * 6 * 4);
    int*   deg    = (int*)carve((size_t)Nn * 4);
    int*   offs   = (int*)carve((size_t)(Nn + 1) * 4);
    int*   cursor = (int*)carve((size_t)Nn * 4);
    int*   csr    = (int*)carve((size_t)Etot * 4);
    uint_t* gmaxu = (uint_t*)carve(18 * 4);
    int*   bsum   = (int*)carve(64 * 4);
    int*   bexcl  = (int*)carve(64 * 4);

    // -------- CSR build --------
    hipMemsetAsync(deg, 0, (size_t)Nn * 4, stream);
    hipMemsetAsync(gmaxu, 0, 18 * 4, stream);   // 0 == fmap(-inf) lower bound
    {
        int nb = (Etot + 255) / 256;
        int nsb = (Nn + 1023) / 1024;
        deg_kernel<<<nb, 256, 0, stream>>>(ei, E, Nn, deg);
        scan1_kernel<<<nsb, 1024, 0, stream>>>(deg, offs, bsum, Nn);
        scan2_kernel<<<1, 64, 0, stream>>>(bsum, bexcl, nsb);
        scan3_kernel<<<(Nn + 255) / 256, 256, 0, stream>>>(deg, offs, bexcl, cursor, Nn);
        scatter_kernel<<<nb, 256, 0, stream>>>(ei, E, Nn, cursor, csr);
    }

    // -------- weight + input prep --------
    {
        int n4 = Nn * 128 / 4;
        split_kernel<<<(n4 + 255) / 256, 256, 0, stream>>>(
            (const float4*)x, (ushort4*)x_hi, (ushort4*)x_lo, n4);
        int wtot = 128 * 256 + 256 * 256 + 256 * 384;
        wprep_all<<<(wtot + 255) / 256, 256, 0, stream>>>(W1, W2, W3, w1hi, w1lo,
                                                          w2hi, w2lo, w3hi, w3lo);
    }

    const int node_blocks = (Nn + 3) / 4;
    const int gemm_rows = (Nn + 63) / 64;

    // -------- layer 1: [50000,128] @ [128,256], H=4, concat+ELU --------
    {
        dim3 g(2, gemm_rows);
        gemm_fused<4><<<g, 256, 0, stream>>>(x_hi, x_lo, w1hi, w1lo, h16,
                                             ssrc, sdst, gmaxu + 0, a1s, a1d, Nn, 128);
        agg_kernel<4, false><<<node_blocks, 256, 0, stream>>>(h16, ssrc, sdst, gmaxu + 0,
                                                              offs, csr, b1,
                                                              nullptr, x1_hi, x1_lo, Nn);
    }
    // -------- layer 2: [50000,256] @ [256,256], H=4, concat+ELU --------
    {
        dim3 g(2, gemm_rows);
        gemm_fused<4><<<g, 256, 0, stream>>>(x1_hi, x1_lo, w2hi, w2lo, h16,
                                             ssrc, sdst, gmaxu + 6, a2s, a2d, Nn, 256);
        agg_kernel<4, false><<<node_blocks, 256, 0, stream>>>(h16, ssrc, sdst, gmaxu + 6,
                                                              offs, csr, b2,
                                                              nullptr, x1_hi, x1_lo, Nn);
    }
    // -------- layer 3: [50000,256] @ [256,384], H=6, mean --------
    {
        dim3 g(3, gemm_rows);
        gemm_fused<6><<<g, 256, 0, stream>>>(x1_hi, x1_lo, w3hi, w3lo, h16,
                                             ssrc, sdst, gmaxu + 12, a3s, a3d, Nn, 256);
        agg_kernel<6, true><<<node_blocks, 256, 0, stream>>>(h16, ssrc, sdst, gmaxu + 12,
                                                             offs, csr, b3,
                                                             out, nullptr, nullptr, Nn);
    }
}